// Round 1
// baseline (1465.092 us; speedup 1.0000x reference)
//
#include <hip/hip_runtime.h>

#define N_NODES 100000
#define N_EDGES 800000
#define G_GRAPHS 64
#define F_INPUT 64
#define H_DIM 128
#define C_OUT 4

// ---------------------------------------------------------------------------
// degree: deg[n] = #edges with dst==n  (float, exact for small counts)
__global__ void deg_kernel(const int* __restrict__ dst, float* __restrict__ deg) {
    int e = blockIdx.x * 256 + threadIdx.x;
    if (e < N_EDGES) unsafeAtomicAdd(&deg[dst[e]], 1.0f);
}

// dinv[n] = rsqrt(deg + 1)   (in place)
__global__ void dinv_kernel(float* __restrict__ deg) {
    int i = blockIdx.x * 256 + threadIdx.x;
    if (i < N_NODES) deg[i] = rsqrtf(deg[i] + 1.0f);
}

// ---------------------------------------------------------------------------
// A = B = (in @ W) * dinv[row]
// block = 256 threads, 32 rows per block (N divides evenly: 100000 = 32*3125).
// W staged in 64-row LDS chunks (32 KB), X^T staged in LDS (stride 36 pads banks).
// Each thread: 4 rows x 4 cols register tile -> 16 FMA per 2 LDS b128 reads.
// In-place safe (in == A): X fully staged to LDS before any A store; blocks own
// disjoint row ranges.
template <int K>
__global__ __launch_bounds__(256) void gemm_scale_kernel(
    const float* __restrict__ in, const float* __restrict__ W,
    const float* __restrict__ dinv, float* __restrict__ A, float* __restrict__ B)
{
    __shared__ float Wl[64 * H_DIM];   // 32 KB
    __shared__ float Xt[K * 36];       // 18 KB (K=128) / 9 KB (K=64)

    const int row0 = blockIdx.x * 32;
    const int tid  = threadIdx.x;

    // stage X^T: Xt[k*36 + r] = in[(row0+r)*K + k]  (coalesced global reads)
    for (int idx = tid; idx < 32 * K; idx += 256) {
        const int k = idx & (K - 1);
        const int r = idx / K;
        Xt[k * 36 + r] = in[(size_t)(row0 + r) * K + k];
    }

    const int f4 = (tid & 31) << 2;   // output column group (4 cols)
    const int r4 = (tid >> 5) << 2;   // output row group (4 rows)

    float acc[4][4];
    #pragma unroll
    for (int i = 0; i < 4; i++)
        #pragma unroll
        for (int j = 0; j < 4; j++) acc[i][j] = 0.0f;

    #pragma unroll
    for (int p = 0; p < K / 64; p++) {
        __syncthreads();                      // previous phase compute done (also fences Xt stage)
        for (int idx = tid; idx < 64 * H_DIM; idx += 256)
            Wl[idx] = W[p * 64 * H_DIM + idx];
        __syncthreads();
        for (int kk = 0; kk < 64; kk++) {
            const int k = p * 64 + kk;
            const float4 wv = *(const float4*)(Wl + kk * H_DIM + f4);
            const float4 xv = *(const float4*)(Xt + k * 36 + r4);
            const float wf[4] = {wv.x, wv.y, wv.z, wv.w};
            const float xf[4] = {xv.x, xv.y, xv.z, xv.w};
            #pragma unroll
            for (int ri = 0; ri < 4; ri++)
                #pragma unroll
                for (int fi = 0; fi < 4; fi++)
                    acc[ri][fi] = fmaf(xf[ri], wf[fi], acc[ri][fi]);
        }
    }

    #pragma unroll
    for (int ri = 0; ri < 4; ri++) {
        const int row = row0 + r4 + ri;
        const float dv = dinv[row];
        float4 v;
        v.x = acc[ri][0] * dv; v.y = acc[ri][1] * dv;
        v.z = acc[ri][2] * dv; v.w = acc[ri][3] * dv;
        *(float4*)(A + (size_t)row * H_DIM + f4) = v;
        *(float4*)(B + (size_t)row * H_DIM + f4) = v;
    }
}

// ---------------------------------------------------------------------------
// B[dst] += A[src]  over all edges, per-feature atomics.
// idx = e*128 + f ; 2 edges per 256-thread block; A row reads coalesced.
__global__ __launch_bounds__(256) void scatter_kernel(
    const float* __restrict__ A, const int* __restrict__ src,
    const int* __restrict__ dst, float* __restrict__ B)
{
    int idx = blockIdx.x * 256 + threadIdx.x;   // < E*128 = 102.4M, fits int32
    int e = idx >> 7;
    int f = idx & 127;
    if (e < N_EDGES) {
        int s = src[e];
        int d = dst[e];
        unsafeAtomicAdd(&B[(size_t)d * H_DIM + f], A[(size_t)s * H_DIM + f]);
    }
}

// ---------------------------------------------------------------------------
// A[i,f] = maybe_relu( B[i,f]*dinv[i] + bias[f] )
template <bool RELU>
__global__ __launch_bounds__(256) void finalize_kernel(
    const float* __restrict__ B, const float* __restrict__ dinv,
    const float* __restrict__ bias, float* __restrict__ A)
{
    int idx = blockIdx.x * 256 + threadIdx.x;   // N*H = 12.8M, exact multiple of 256
    int i = idx >> 7;
    int f = idx & 127;
    float v = B[idx] * dinv[i] + bias[f];
    if (RELU) v = fmaxf(v, 0.0f);
    A[idx] = v;
}

// ---------------------------------------------------------------------------
// mean-pool per graph: batch is sorted, so each block's row range spans few
// graphs -> register-accumulate runs, flush with one atomic per (run, feature).
__global__ __launch_bounds__(128) void pool_kernel(
    const float* __restrict__ A, const int* __restrict__ batch,
    float* __restrict__ s, float* __restrict__ cnt)
{
    const int RPB = 256;
    int row0 = blockIdx.x * RPB;
    int f = threadIdx.x;
    float acc = 0.0f;
    int cur = -1, c = 0;
    for (int r = 0; r < RPB; r++) {
        int row = row0 + r;
        if (row >= N_NODES) break;
        int g = batch[row];
        if (g != cur) {
            if (cur >= 0) {
                unsafeAtomicAdd(&s[cur * H_DIM + f], acc);
                if (f == 0) unsafeAtomicAdd(&cnt[cur], (float)c);
            }
            cur = g; acc = 0.0f; c = 0;
        }
        acc += A[(size_t)row * H_DIM + f];
        c++;
    }
    if (cur >= 0) {
        unsafeAtomicAdd(&s[cur * H_DIM + f], acc);
        if (f == 0) unsafeAtomicAdd(&cnt[cur], (float)c);
    }
}

// ---------------------------------------------------------------------------
// final MLP: one block per graph.
__global__ __launch_bounds__(128) void mlp_kernel(
    const float* __restrict__ s, const float* __restrict__ cnt,
    const float* __restrict__ fw1, const float* __restrict__ fb1,
    const float* __restrict__ fw2, const float* __restrict__ fb2,
    float* __restrict__ out)
{
    __shared__ float p[H_DIM];
    __shared__ float z[H_DIM];
    int g = blockIdx.x;
    int f = threadIdx.x;
    float c = fmaxf(cnt[g], 1.0f);
    p[f] = s[g * H_DIM + f] / c;
    __syncthreads();
    float acc = fb1[f];
    for (int k = 0; k < H_DIM; k++) acc = fmaf(p[k], fw1[k * H_DIM + f], acc);
    z[f] = fmaxf(acc, 0.0f);
    __syncthreads();
    if (f < C_OUT) {
        float o = fb2[f];
        for (int k = 0; k < H_DIM; k++) o = fmaf(z[k], fw2[k * C_OUT + f], o);
        out[g * C_OUT + f] = o;
    }
}

// ---------------------------------------------------------------------------
extern "C" void kernel_launch(void* const* d_in, const int* in_sizes, int n_in,
                              void* d_out, int out_size, void* d_ws, size_t ws_size,
                              hipStream_t stream)
{
    const float* x   = (const float*)d_in[0];
    const float* W1  = (const float*)d_in[1];
    const float* b1  = (const float*)d_in[2];
    const float* W2  = (const float*)d_in[3];
    const float* b2  = (const float*)d_in[4];
    const float* W3  = (const float*)d_in[5];
    const float* b3  = (const float*)d_in[6];
    const float* fw1 = (const float*)d_in[7];
    const float* fb1 = (const float*)d_in[8];
    const float* fw2 = (const float*)d_in[9];
    const float* fb2 = (const float*)d_in[10];
    const int*   ei  = (const int*)d_in[11];
    const int*   bat = (const int*)d_in[12];
    const int* esrc = ei;
    const int* edst = ei + N_EDGES;
    float* out = (float*)d_out;

    float* A    = (float*)d_ws;                       // N*H
    float* B    = A + (size_t)N_NODES * H_DIM;        // N*H
    float* dinv = B + (size_t)N_NODES * H_DIM;        // N
    float* s    = dinv + N_NODES;                     // G*H
    float* cnt  = s + G_GRAPHS * H_DIM;               // G

    // zero deg and pool accumulators (ws is poisoned 0xAA before every call)
    hipMemsetAsync(dinv, 0, N_NODES * sizeof(float), stream);
    hipMemsetAsync(s, 0, (G_GRAPHS * H_DIM + G_GRAPHS) * sizeof(float), stream);

    deg_kernel<<<(N_EDGES + 255) / 256, 256, 0, stream>>>(edst, dinv);
    dinv_kernel<<<(N_NODES + 255) / 256, 256, 0, stream>>>(dinv);

    const int gemm_grid = N_NODES / 32;             // 3125, exact
    const int scat_grid = N_EDGES / 2;              // 400000 blocks (E*128/256)
    const int fin_grid  = (N_NODES * H_DIM) / 256;  // 50000, exact

    // layer 1 (K = 64)
    gemm_scale_kernel<64><<<gemm_grid, 256, 0, stream>>>(x, W1, dinv, A, B);
    scatter_kernel<<<scat_grid, 256, 0, stream>>>(A, esrc, edst, B);
    finalize_kernel<true><<<fin_grid, 256, 0, stream>>>(B, dinv, b1, A);

    // layer 2 (K = 128, in-place on A)
    gemm_scale_kernel<128><<<gemm_grid, 256, 0, stream>>>(A, W2, dinv, A, B);
    scatter_kernel<<<scat_grid, 256, 0, stream>>>(A, esrc, edst, B);
    finalize_kernel<true><<<fin_grid, 256, 0, stream>>>(B, dinv, b2, A);

    // layer 3 (K = 128, no relu)
    gemm_scale_kernel<128><<<gemm_grid, 256, 0, stream>>>(A, W3, dinv, A, B);
    scatter_kernel<<<scat_grid, 256, 0, stream>>>(A, esrc, edst, B);
    finalize_kernel<false><<<fin_grid, 256, 0, stream>>>(B, dinv, b3, A);

    // pool + MLP head
    pool_kernel<<<(N_NODES + 255) / 256, 128, 0, stream>>>(A, bat, s, cnt);
    mlp_kernel<<<G_GRAPHS, 128, 0, stream>>>(s, cnt, fw1, fb1, fw2, fb2, out);
}

// Round 2
// 898.142 us; speedup vs baseline: 1.6312x; 1.6312x over previous
//
#include <hip/hip_runtime.h>

#define N_NODES 100000
#define N_EDGES 800000
#define G_GRAPHS 64
#define F_INPUT 64
#define H_DIM 128
#define C_OUT 4
#define SCAN_BLOCKS ((N_NODES + 255) / 256)   // 391

// ---------------------------------------------------------------------------
// CSR build step 1: in-degree histogram (int counts)
__global__ void hist_kernel(const int* __restrict__ dst, int* __restrict__ cnt) {
    int e = blockIdx.x * 256 + threadIdx.x;
    if (e < N_EDGES) atomicAdd(&cnt[dst[e]], 1);
}

// step 2a: per-block exclusive scan of counts; block sums out
__global__ __launch_bounds__(256) void scan1_kernel(
    const int* __restrict__ cnt, int* __restrict__ pre, int* __restrict__ bsum)
{
    __shared__ int tmp[256];
    int i = blockIdx.x * 256 + threadIdx.x;
    int v = (i < N_NODES) ? cnt[i] : 0;
    tmp[threadIdx.x] = v;
    __syncthreads();
    for (int off = 1; off < 256; off <<= 1) {
        int t = (threadIdx.x >= off) ? tmp[threadIdx.x - off] : 0;
        __syncthreads();
        tmp[threadIdx.x] += t;
        __syncthreads();
    }
    if (i < N_NODES) pre[i] = tmp[threadIdx.x] - v;   // exclusive
    if (threadIdx.x == 255) bsum[blockIdx.x] = tmp[255];
}

// step 2b: exclusive scan of the 391 block sums (single block, LDS serial)
__global__ __launch_bounds__(512) void scan2_kernel(int* __restrict__ bsum) {
    __shared__ int t[SCAN_BLOCKS];
    int tid = threadIdx.x;
    if (tid < SCAN_BLOCKS) t[tid] = bsum[tid];
    __syncthreads();
    if (tid == 0) {
        int run = 0;
        for (int i = 0; i < SCAN_BLOCKS; i++) { int v = t[i]; t[i] = run; run += v; }
    }
    __syncthreads();
    if (tid < SCAN_BLOCKS) bsum[tid] = t[tid];
}

// step 2c: offsets = pre + bsum[block]; also dinv = rsqrt(cnt+1)
__global__ __launch_bounds__(256) void scan3_kernel(
    const int* __restrict__ pre, const int* __restrict__ bsum,
    const int* __restrict__ cnt, int* __restrict__ offs, float* __restrict__ dinv)
{
    int i = blockIdx.x * 256 + threadIdx.x;
    if (i < N_NODES) {
        offs[i] = pre[i] + bsum[blockIdx.x];
        dinv[i] = rsqrtf((float)cnt[i] + 1.0f);
    }
    if (i == 0) offs[N_NODES] = N_EDGES;
}

// step 3: fill CSR; atomicSub on the count array as per-node cursor
__global__ void fill_kernel(const int* __restrict__ src, const int* __restrict__ dst,
                            const int* __restrict__ offs, int* __restrict__ cnt,
                            int* __restrict__ csr)
{
    int e = blockIdx.x * 256 + threadIdx.x;
    if (e < N_EDGES) {
        int d = dst[e];
        int p = offs[d] + (atomicSub(&cnt[d], 1) - 1);
        csr[p] = src[e];
    }
}

// ---------------------------------------------------------------------------
// hs = (in @ W) * dinv[row]
// block = 256 threads, 32 rows per block. W staged in 64-row LDS chunks,
// X^T staged in LDS (stride 36). 4x4 register tile per thread.
template <int K>
__global__ __launch_bounds__(256) void gemm_scale_kernel(
    const float* __restrict__ in, const float* __restrict__ W,
    const float* __restrict__ dinv, float* __restrict__ A)
{
    __shared__ float Wl[64 * H_DIM];   // 32 KB
    __shared__ float Xt[K * 36];

    const int row0 = blockIdx.x * 32;
    const int tid  = threadIdx.x;

    for (int idx = tid; idx < 32 * K; idx += 256) {
        const int k = idx & (K - 1);
        const int r = idx / K;
        Xt[k * 36 + r] = in[(size_t)(row0 + r) * K + k];
    }

    const int f4 = (tid & 31) << 2;
    const int r4 = (tid >> 5) << 2;

    float acc[4][4];
    #pragma unroll
    for (int i = 0; i < 4; i++)
        #pragma unroll
        for (int j = 0; j < 4; j++) acc[i][j] = 0.0f;

    #pragma unroll
    for (int p = 0; p < K / 64; p++) {
        __syncthreads();
        for (int idx = tid; idx < 64 * H_DIM; idx += 256)
            Wl[idx] = W[p * 64 * H_DIM + idx];
        __syncthreads();
        for (int kk = 0; kk < 64; kk++) {
            const int k = p * 64 + kk;
            const float4 wv = *(const float4*)(Wl + kk * H_DIM + f4);
            const float4 xv = *(const float4*)(Xt + k * 36 + r4);
            const float wf[4] = {wv.x, wv.y, wv.z, wv.w};
            const float xf[4] = {xv.x, xv.y, xv.z, xv.w};
            #pragma unroll
            for (int ri = 0; ri < 4; ri++)
                #pragma unroll
                for (int fi = 0; fi < 4; fi++)
                    acc[ri][fi] = fmaf(xf[ri], wf[fi], acc[ri][fi]);
        }
    }

    #pragma unroll
    for (int ri = 0; ri < 4; ri++) {
        const int row = row0 + r4 + ri;
        const float dv = dinv[row];
        float4 v;
        v.x = acc[ri][0] * dv; v.y = acc[ri][1] * dv;
        v.z = acc[ri][2] * dv; v.w = acc[ri][3] * dv;
        *(float4*)(A + (size_t)row * H_DIM + f4) = v;
    }
}

// ---------------------------------------------------------------------------
// gather + finalize: out[i,f] = maybe_relu( dinv[i]*(hs[i,f] + sum_e hs[csr[e],f]) + bias[f] )
// thread (i,f): 128-thread group per node; per-edge row reads coalesced.
template <bool RELU>
__global__ __launch_bounds__(256) void gather_kernel(
    const float* __restrict__ hs, const int* __restrict__ offs,
    const int* __restrict__ csr, const float* __restrict__ dinv,
    const float* __restrict__ bias, float* __restrict__ out)
{
    int idx = blockIdx.x * 256 + threadIdx.x;   // N*H = 12.8M
    int i = idx >> 7;
    int f = idx & 127;
    int beg = offs[i];
    int end = offs[i + 1];
    float acc = hs[idx];
    int e = beg;
    int s_next = (e < end) ? csr[e] : 0;
    while (e < end) {
        int s = s_next;
        e++;
        s_next = (e < end) ? csr[e] : 0;
        acc += hs[(size_t)s * H_DIM + f];
    }
    float v = acc * dinv[i] + bias[f];
    if (RELU) v = fmaxf(v, 0.0f);
    out[idx] = v;
}

// ---------------------------------------------------------------------------
// mean-pool per graph (batch sorted -> run-accumulate, atomic flush per run)
__global__ __launch_bounds__(128) void pool_kernel(
    const float* __restrict__ A, const int* __restrict__ batch,
    float* __restrict__ s, float* __restrict__ cnt)
{
    const int RPB = 256;
    int row0 = blockIdx.x * RPB;
    int f = threadIdx.x;
    float acc = 0.0f;
    int cur = -1, c = 0;
    for (int r = 0; r < RPB; r++) {
        int row = row0 + r;
        if (row >= N_NODES) break;
        int g = batch[row];
        if (g != cur) {
            if (cur >= 0) {
                unsafeAtomicAdd(&s[cur * H_DIM + f], acc);
                if (f == 0) unsafeAtomicAdd(&cnt[cur], (float)c);
            }
            cur = g; acc = 0.0f; c = 0;
        }
        acc += A[(size_t)row * H_DIM + f];
        c++;
    }
    if (cur >= 0) {
        unsafeAtomicAdd(&s[cur * H_DIM + f], acc);
        if (f == 0) unsafeAtomicAdd(&cnt[cur], (float)c);
    }
}

// ---------------------------------------------------------------------------
// final MLP: one block per graph.
__global__ __launch_bounds__(128) void mlp_kernel(
    const float* __restrict__ s, const float* __restrict__ cnt,
    const float* __restrict__ fw1, const float* __restrict__ fb1,
    const float* __restrict__ fw2, const float* __restrict__ fb2,
    float* __restrict__ out)
{
    __shared__ float p[H_DIM];
    __shared__ float z[H_DIM];
    int g = blockIdx.x;
    int f = threadIdx.x;
    float c = fmaxf(cnt[g], 1.0f);
    p[f] = s[g * H_DIM + f] / c;
    __syncthreads();
    float acc = fb1[f];
    for (int k = 0; k < H_DIM; k++) acc = fmaf(p[k], fw1[k * H_DIM + f], acc);
    z[f] = fmaxf(acc, 0.0f);
    __syncthreads();
    if (f < C_OUT) {
        float o = fb2[f];
        for (int k = 0; k < H_DIM; k++) o = fmaf(z[k], fw2[k * C_OUT + f], o);
        out[g * C_OUT + f] = o;
    }
}

// ---------------------------------------------------------------------------
extern "C" void kernel_launch(void* const* d_in, const int* in_sizes, int n_in,
                              void* d_out, int out_size, void* d_ws, size_t ws_size,
                              hipStream_t stream)
{
    const float* x   = (const float*)d_in[0];
    const float* W1  = (const float*)d_in[1];
    const float* b1  = (const float*)d_in[2];
    const float* W2  = (const float*)d_in[3];
    const float* b2  = (const float*)d_in[4];
    const float* W3  = (const float*)d_in[5];
    const float* b3  = (const float*)d_in[6];
    const float* fw1 = (const float*)d_in[7];
    const float* fb1 = (const float*)d_in[8];
    const float* fw2 = (const float*)d_in[9];
    const float* fb2 = (const float*)d_in[10];
    const int*   ei  = (const int*)d_in[11];
    const int*   bat = (const int*)d_in[12];
    const int* esrc = ei;
    const int* edst = ei + N_EDGES;
    float* out = (float*)d_out;

    // workspace layout
    float* hsA  = (float*)d_ws;                        // N*H floats
    float* hB   = hsA + (size_t)N_NODES * H_DIM;       // N*H floats
    float* dinv = hB + (size_t)N_NODES * H_DIM;        // N floats
    float* s    = dinv + N_NODES;                      // G*H floats
    float* cnt  = s + G_GRAPHS * H_DIM;                // G floats
    int*   cnti = (int*)(cnt + G_GRAPHS);              // N ints
    int*   pre  = cnti + N_NODES;                      // N ints
    int*   offs = pre + N_NODES;                       // N+1 ints
    int*   bsum = offs + N_NODES + 1;                  // SCAN_BLOCKS ints
    int*   csr  = bsum + SCAN_BLOCKS + 1;              // E ints

    // zero int counts + pool accumulators (ws poisoned 0xAA each call)
    hipMemsetAsync(cnti, 0, N_NODES * sizeof(int), stream);
    hipMemsetAsync(s, 0, (G_GRAPHS * H_DIM + G_GRAPHS) * sizeof(float), stream);

    // CSR build
    const int egrid = (N_EDGES + 255) / 256;
    hist_kernel<<<egrid, 256, 0, stream>>>(edst, cnti);
    scan1_kernel<<<SCAN_BLOCKS, 256, 0, stream>>>(cnti, pre, bsum);
    scan2_kernel<<<1, 512, 0, stream>>>(bsum);
    scan3_kernel<<<SCAN_BLOCKS, 256, 0, stream>>>(pre, bsum, cnti, offs, dinv);
    fill_kernel<<<egrid, 256, 0, stream>>>(esrc, edst, offs, cnti, csr);

    const int gemm_grid = N_NODES / 32;               // 3125
    const int gath_grid = (N_NODES * H_DIM) / 256;    // 50000

    // layer 1 (K=64)
    gemm_scale_kernel<64><<<gemm_grid, 256, 0, stream>>>(x, W1, dinv, hsA);
    gather_kernel<true><<<gath_grid, 256, 0, stream>>>(hsA, offs, csr, dinv, b1, hB);
    // layer 2
    gemm_scale_kernel<128><<<gemm_grid, 256, 0, stream>>>(hB, W2, dinv, hsA);
    gather_kernel<true><<<gath_grid, 256, 0, stream>>>(hsA, offs, csr, dinv, b2, hB);
    // layer 3
    gemm_scale_kernel<128><<<gemm_grid, 256, 0, stream>>>(hB, W3, dinv, hsA);
    gather_kernel<false><<<gath_grid, 256, 0, stream>>>(hsA, offs, csr, dinv, b3, hB);

    // pool + MLP head
    pool_kernel<<<(N_NODES + 255) / 256, 128, 0, stream>>>(hB, bat, s, cnt);
    mlp_kernel<<<G_GRAPHS, 128, 0, stream>>>(s, cnt, fw1, fb1, fw2, fb2, out);
}

// Round 3
// 625.862 us; speedup vs baseline: 2.3409x; 1.4350x over previous
//
#include <hip/hip_runtime.h>

#define N_NODES 100000
#define N_EDGES 800000
#define G_GRAPHS 64
#define F_INPUT 64
#define H_DIM 128
#define C_OUT 4
#define SCAN_BLOCKS ((N_NODES + 255) / 256)   // 391

typedef __attribute__((ext_vector_type(8))) short bf16x8;
typedef __attribute__((ext_vector_type(8))) unsigned short u16x8;
typedef __attribute__((ext_vector_type(4))) float f32x4;

__device__ inline unsigned short f2bf(float f) {
    union { float f; unsigned int u; } v; v.f = f;
    unsigned int u = v.u + 0x7FFFu + ((v.u >> 16) & 1u);
    return (unsigned short)(u >> 16);
}
__device__ inline float bf2f(unsigned short b) {
    union { unsigned int u; float f; } v; v.u = ((unsigned int)b) << 16;
    return v.f;
}
__device__ inline float2 unpack_pair(unsigned int u) {
    union { unsigned int u; float f; } a, b;
    a.u = u << 16; b.u = u & 0xFFFF0000u;
    float2 r; r.x = a.f; r.y = b.f; return r;
}

// ---------------------------------------------------------------------------
// CSR build
__global__ void hist_kernel(const int* __restrict__ dst, int* __restrict__ cnt) {
    int e = blockIdx.x * 256 + threadIdx.x;
    if (e < N_EDGES) atomicAdd(&cnt[dst[e]], 1);
}
__global__ __launch_bounds__(256) void scan1_kernel(
    const int* __restrict__ cnt, int* __restrict__ pre, int* __restrict__ bsum)
{
    __shared__ int tmp[256];
    int i = blockIdx.x * 256 + threadIdx.x;
    int v = (i < N_NODES) ? cnt[i] : 0;
    tmp[threadIdx.x] = v;
    __syncthreads();
    for (int off = 1; off < 256; off <<= 1) {
        int t = (threadIdx.x >= off) ? tmp[threadIdx.x - off] : 0;
        __syncthreads();
        tmp[threadIdx.x] += t;
        __syncthreads();
    }
    if (i < N_NODES) pre[i] = tmp[threadIdx.x] - v;
    if (threadIdx.x == 255) bsum[blockIdx.x] = tmp[255];
}
__global__ __launch_bounds__(512) void scan2_kernel(int* __restrict__ bsum) {
    __shared__ int t[SCAN_BLOCKS];
    int tid = threadIdx.x;
    if (tid < SCAN_BLOCKS) t[tid] = bsum[tid];
    __syncthreads();
    if (tid == 0) {
        int run = 0;
        for (int i = 0; i < SCAN_BLOCKS; i++) { int v = t[i]; t[i] = run; run += v; }
    }
    __syncthreads();
    if (tid < SCAN_BLOCKS) bsum[tid] = t[tid];
}
__global__ __launch_bounds__(256) void scan3_kernel(
    const int* __restrict__ pre, const int* __restrict__ bsum,
    const int* __restrict__ cnt, int* __restrict__ offs, float* __restrict__ dinv)
{
    int i = blockIdx.x * 256 + threadIdx.x;
    if (i < N_NODES) {
        offs[i] = pre[i] + bsum[blockIdx.x];
        dinv[i] = rsqrtf((float)cnt[i] + 1.0f);
    }
    if (i == 0) offs[N_NODES] = N_EDGES;
}
__global__ void fill_kernel(const int* __restrict__ src, const int* __restrict__ dst,
                            const int* __restrict__ offs, int* __restrict__ cnt,
                            int* __restrict__ csr)
{
    int e = blockIdx.x * 256 + threadIdx.x;
    if (e < N_EDGES) {
        int d = dst[e];
        int p = offs[d] + (atomicSub(&cnt[d], 1) - 1);
        csr[p] = src[e];
    }
}

// ---------------------------------------------------------------------------
// x (fp32 [N,64]) -> bf16
__global__ __launch_bounds__(256) void convert_x_kernel(
    const float4* __restrict__ x4, unsigned int* __restrict__ xb_u)
{
    int i = blockIdx.x * 256 + threadIdx.x;   // N*64/4 = 1.6M
    if (i < N_NODES * F_INPUT / 4) {
        float4 v = x4[i];
        xb_u[i * 2 + 0] = (unsigned int)f2bf(v.x) | ((unsigned int)f2bf(v.y) << 16);
        xb_u[i * 2 + 1] = (unsigned int)f2bf(v.z) | ((unsigned int)f2bf(v.w) << 16);
    }
}

// W [K,H] fp32 -> transposed split bf16 pair: whi/wlo [H,K]
__global__ void wsplit_kernel(const float* __restrict__ W, unsigned short* __restrict__ hi,
                              unsigned short* __restrict__ lo, int K)
{
    int idx = blockIdx.x * 256 + threadIdx.x;
    if (idx < K * H_DIM) {
        int k = idx / H_DIM, n = idx % H_DIM;
        float w = W[idx];
        unsigned short h = f2bf(w);
        unsigned short l = f2bf(w - bf2f(h));
        hi[n * K + k] = h;
        lo[n * K + k] = l;
    }
}

// ---------------------------------------------------------------------------
// MFMA GEMM: out[N,H]bf16 = (in[N,K]bf16 @ (Whi+Wlo)[K,H]) * dinv[row]
// 128-row x 128-col tile per 256-thread block (4 waves, 32 rows/wave).
// LDS in fragment-contiguous tiled layout: tile (mt, ks) stores its 64 lanes'
// 16B fragments consecutively -> conflict-free ds_read_b128 + coalesced stage.
template <int K>
__global__ __launch_bounds__(256) void mfma_gemm_kernel(
    const unsigned short* __restrict__ in, const unsigned short* __restrict__ whi,
    const unsigned short* __restrict__ wlo, const float* __restrict__ dinv,
    unsigned short* __restrict__ out)
{
    constexpr int KS = K / 32;                 // k-steps
    __shared__ unsigned short As[128 * K];     // A tiles   (K=128: 32 KB)
    __shared__ unsigned short Bh[128 * K];     // Whi^T tiles
    __shared__ unsigned short Bl[128 * K];     // Wlo^T tiles

    const int tid  = threadIdx.x;
    const int row0 = blockIdx.x * 128;

    // stage: c enumerates (mt, ks, lane); global reads coalesce in 64B/row runs
    const int CH = 128 * K / 8;                // chunks of 8 elems
    for (int c = tid; c < CH; c += 256) {
        int mt   = c / (KS * 64);
        int rest = c % (KS * 64);
        int ks   = rest / 64;
        int lane = rest % 64;
        int r    = mt * 16 + (lane & 15);
        int k    = ks * 32 + (lane >> 4) * 8;
        int gr   = row0 + r; if (gr >= N_NODES) gr = N_NODES - 1;
        *(u16x8*)(As + c * 8) = *(const u16x8*)(in + (size_t)gr * K + k);
        *(u16x8*)(Bh + c * 8) = *(const u16x8*)(whi + (size_t)r * K + k);
        *(u16x8*)(Bl + c * 8) = *(const u16x8*)(wlo + (size_t)r * K + k);
    }
    __syncthreads();

    const int w = tid >> 6, lane = tid & 63;
    const int quad = lane >> 4, l16 = lane & 15;

    f32x4 acc[2][8];
    #pragma unroll
    for (int rt = 0; rt < 2; rt++)
        #pragma unroll
        for (int ct = 0; ct < 8; ct++) acc[rt][ct] = (f32x4)(0.0f);

    #pragma unroll
    for (int ks = 0; ks < KS; ks++) {
        bf16x8 a0 = *(const bf16x8*)(As + (((w * 2 + 0) * KS + ks) * 64 + lane) * 8);
        bf16x8 a1 = *(const bf16x8*)(As + (((w * 2 + 1) * KS + ks) * 64 + lane) * 8);
        bf16x8 bh[8], bl[8];
        #pragma unroll
        for (int ct = 0; ct < 8; ct++) {
            bh[ct] = *(const bf16x8*)(Bh + ((ct * KS + ks) * 64 + lane) * 8);
            bl[ct] = *(const bf16x8*)(Bl + ((ct * KS + ks) * 64 + lane) * 8);
        }
        #pragma unroll
        for (int ct = 0; ct < 8; ct++) {
            acc[0][ct] = __builtin_amdgcn_mfma_f32_16x16x32_bf16(a0, bh[ct], acc[0][ct], 0, 0, 0);
            acc[0][ct] = __builtin_amdgcn_mfma_f32_16x16x32_bf16(a0, bl[ct], acc[0][ct], 0, 0, 0);
            acc[1][ct] = __builtin_amdgcn_mfma_f32_16x16x32_bf16(a1, bh[ct], acc[1][ct], 0, 0, 0);
            acc[1][ct] = __builtin_amdgcn_mfma_f32_16x16x32_bf16(a1, bl[ct], acc[1][ct], 0, 0, 0);
        }
    }

    // epilogue: C/D layout col=lane&15, row=quad*4+reg (within 16-row tile)
    #pragma unroll
    for (int rt = 0; rt < 2; rt++) {
        #pragma unroll
        for (int reg = 0; reg < 4; reg++) {
            int row = row0 + w * 32 + rt * 16 + quad * 4 + reg;
            if (row < N_NODES) {
                float dv = dinv[row];
                #pragma unroll
                for (int ct = 0; ct < 8; ct++)
                    out[(size_t)row * H_DIM + ct * 16 + l16] = f2bf(acc[rt][ct][reg] * dv);
            }
        }
    }
}

// ---------------------------------------------------------------------------
// gather + finalize over bf16 hs: thread = (node i, feature-pair f2).
// out = maybe_relu(dinv[i]*(hs[i]+sum hs[csr]) + bias); OUT_BF16 -> packed pair
template <bool RELU, bool OUT_BF16>
__global__ __launch_bounds__(256) void gather_kernel(
    const unsigned int* __restrict__ hs_u, const int* __restrict__ offs,
    const int* __restrict__ csr, const float* __restrict__ dinv,
    const float* __restrict__ bias, unsigned int* __restrict__ outb,
    float2* __restrict__ outf)
{
    int idx = blockIdx.x * 256 + threadIdx.x;   // N*64 = 6.4M
    int i = idx >> 6;
    int f2 = idx & 63;
    int beg = offs[i];
    int end = offs[i + 1];
    float2 acc = unpack_pair(hs_u[(size_t)i * 64 + f2]);
    int e = beg;
    int s_next = (e < end) ? csr[e] : 0;
    while (e < end) {
        int s = s_next;
        e++;
        s_next = (e < end) ? csr[e] : 0;
        float2 v = unpack_pair(hs_u[(size_t)s * 64 + f2]);
        acc.x += v.x; acc.y += v.y;
    }
    float dv = dinv[i];
    float2 bv = *(const float2*)(bias + f2 * 2);
    float vx = acc.x * dv + bv.x;
    float vy = acc.y * dv + bv.y;
    if (RELU) { vx = fmaxf(vx, 0.0f); vy = fmaxf(vy, 0.0f); }
    if (OUT_BF16) {
        outb[idx] = (unsigned int)f2bf(vx) | ((unsigned int)f2bf(vy) << 16);
    } else {
        float2 o; o.x = vx; o.y = vy;
        outf[idx] = o;
    }
}

// ---------------------------------------------------------------------------
// mean-pool per graph over bf16 node features (batch sorted -> run-accumulate)
__global__ __launch_bounds__(128) void pool_kernel(
    const unsigned short* __restrict__ A, const int* __restrict__ batch,
    float* __restrict__ s, float* __restrict__ cnt)
{
    const int RPB = 256;
    int row0 = blockIdx.x * RPB;
    int f = threadIdx.x;
    float acc = 0.0f;
    int cur = -1, c = 0;
    for (int r = 0; r < RPB; r++) {
        int row = row0 + r;
        if (row >= N_NODES) break;
        int g = batch[row];
        if (g != cur) {
            if (cur >= 0) {
                unsafeAtomicAdd(&s[cur * H_DIM + f], acc);
                if (f == 0) unsafeAtomicAdd(&cnt[cur], (float)c);
            }
            cur = g; acc = 0.0f; c = 0;
        }
        acc += bf2f(A[(size_t)row * H_DIM + f]);
        c++;
    }
    if (cur >= 0) {
        unsafeAtomicAdd(&s[cur * H_DIM + f], acc);
        if (f == 0) unsafeAtomicAdd(&cnt[cur], (float)c);
    }
}

// ---------------------------------------------------------------------------
__global__ __launch_bounds__(128) void mlp_kernel(
    const float* __restrict__ s, const float* __restrict__ cnt,
    const float* __restrict__ fw1, const float* __restrict__ fb1,
    const float* __restrict__ fw2, const float* __restrict__ fb2,
    float* __restrict__ out)
{
    __shared__ float p[H_DIM];
    __shared__ float z[H_DIM];
    int g = blockIdx.x;
    int f = threadIdx.x;
    float c = fmaxf(cnt[g], 1.0f);
    p[f] = s[g * H_DIM + f] / c;
    __syncthreads();
    float acc = fb1[f];
    for (int k = 0; k < H_DIM; k++) acc = fmaf(p[k], fw1[k * H_DIM + f], acc);
    z[f] = fmaxf(acc, 0.0f);
    __syncthreads();
    if (f < C_OUT) {
        float o = fb2[f];
        for (int k = 0; k < H_DIM; k++) o = fmaf(z[k], fw2[k * C_OUT + f], o);
        out[g * C_OUT + f] = o;
    }
}

// ---------------------------------------------------------------------------
extern "C" void kernel_launch(void* const* d_in, const int* in_sizes, int n_in,
                              void* d_out, int out_size, void* d_ws, size_t ws_size,
                              hipStream_t stream)
{
    const float* x   = (const float*)d_in[0];
    const float* W1  = (const float*)d_in[1];
    const float* b1  = (const float*)d_in[2];
    const float* W2  = (const float*)d_in[3];
    const float* b2  = (const float*)d_in[4];
    const float* W3  = (const float*)d_in[5];
    const float* b3  = (const float*)d_in[6];
    const float* fw1 = (const float*)d_in[7];
    const float* fb1 = (const float*)d_in[8];
    const float* fw2 = (const float*)d_in[9];
    const float* fb2 = (const float*)d_in[10];
    const int*   ei  = (const int*)d_in[11];
    const int*   bat = (const int*)d_in[12];
    const int* esrc = ei;
    const int* edst = ei + N_EDGES;
    float* out = (float*)d_out;

    // workspace layout (16B-aligned chunks first)
    char* ws = (char*)d_ws;
    unsigned short* hsb  = (unsigned short*)ws;                      ws += (size_t)N_NODES * H_DIM * 2;   // 25.6MB
    unsigned short* aggb = (unsigned short*)ws;                      ws += (size_t)N_NODES * H_DIM * 2;   // 25.6MB
    unsigned short* xb   = (unsigned short*)ws;                      ws += (size_t)N_NODES * F_INPUT * 2; // 12.8MB
    unsigned short* w1hi = (unsigned short*)ws;  ws += H_DIM * F_INPUT * 2;
    unsigned short* w1lo = (unsigned short*)ws;  ws += H_DIM * F_INPUT * 2;
    unsigned short* w2hi = (unsigned short*)ws;  ws += H_DIM * H_DIM * 2;
    unsigned short* w2lo = (unsigned short*)ws;  ws += H_DIM * H_DIM * 2;
    unsigned short* w3hi = (unsigned short*)ws;  ws += H_DIM * H_DIM * 2;
    unsigned short* w3lo = (unsigned short*)ws;  ws += H_DIM * H_DIM * 2;
    float* dinv = (float*)ws;  ws += N_NODES * 4;
    float* s    = (float*)ws;  ws += G_GRAPHS * H_DIM * 4;
    float* cnt  = (float*)ws;  ws += G_GRAPHS * 4;
    int* cnti   = (int*)ws;    ws += N_NODES * 4;
    int* pre    = (int*)ws;    ws += N_NODES * 4;
    int* offs   = (int*)ws;    ws += (N_NODES + 1) * 4;
    int* bsum   = (int*)ws;    ws += (SCAN_BLOCKS + 1) * 4;
    int* csr    = (int*)ws;    ws += (size_t)N_EDGES * 4;

    hipMemsetAsync(cnti, 0, N_NODES * sizeof(int), stream);
    hipMemsetAsync(s, 0, (G_GRAPHS * H_DIM + G_GRAPHS) * sizeof(float), stream);

    // CSR build
    const int egrid = (N_EDGES + 255) / 256;
    hist_kernel<<<egrid, 256, 0, stream>>>(edst, cnti);
    scan1_kernel<<<SCAN_BLOCKS, 256, 0, stream>>>(cnti, pre, bsum);
    scan2_kernel<<<1, 512, 0, stream>>>(bsum);
    scan3_kernel<<<SCAN_BLOCKS, 256, 0, stream>>>(pre, bsum, cnti, offs, dinv);
    fill_kernel<<<egrid, 256, 0, stream>>>(esrc, edst, offs, cnti, csr);

    // weight prep + x conversion
    convert_x_kernel<<<(N_NODES * F_INPUT / 4 + 255) / 256, 256, 0, stream>>>(
        (const float4*)x, (unsigned int*)xb);
    wsplit_kernel<<<(F_INPUT * H_DIM + 255) / 256, 256, 0, stream>>>(W1, w1hi, w1lo, F_INPUT);
    wsplit_kernel<<<(H_DIM * H_DIM + 255) / 256, 256, 0, stream>>>(W2, w2hi, w2lo, H_DIM);
    wsplit_kernel<<<(H_DIM * H_DIM + 255) / 256, 256, 0, stream>>>(W3, w3hi, w3lo, H_DIM);

    const int gemm_grid = (N_NODES + 127) / 128;        // 782
    const int gath_grid = (N_NODES * 64) / 256;         // 25000

    // layer 1 (K=64)
    mfma_gemm_kernel<64><<<gemm_grid, 256, 0, stream>>>(xb, w1hi, w1lo, dinv, hsb);
    gather_kernel<true, true><<<gath_grid, 256, 0, stream>>>(
        (const unsigned int*)hsb, offs, csr, dinv, b1, (unsigned int*)aggb, nullptr);
    // layer 2 (K=128)
    mfma_gemm_kernel<128><<<gemm_grid, 256, 0, stream>>>(aggb, w2hi, w2lo, dinv, hsb);
    gather_kernel<true, true><<<gath_grid, 256, 0, stream>>>(
        (const unsigned int*)hsb, offs, csr, dinv, b2, (unsigned int*)aggb, nullptr);
    // layer 3 (K=128, no relu)
    mfma_gemm_kernel<128><<<gemm_grid, 256, 0, stream>>>(aggb, w3hi, w3lo, dinv, hsb);
    gather_kernel<false, true><<<gath_grid, 256, 0, stream>>>(
        (const unsigned int*)hsb, offs, csr, dinv, b3, (unsigned int*)aggb, nullptr);

    // pool + MLP head
    pool_kernel<<<(N_NODES + 255) / 256, 128, 0, stream>>>(aggb, bat, s, cnt);
    mlp_kernel<<<G_GRAPHS, 128, 0, stream>>>(s, cnt, fw1, fb1, fw2, fb2, out);
}

// Round 4
// 471.010 us; speedup vs baseline: 3.1105x; 1.3288x over previous
//
#include <hip/hip_runtime.h>

#define N_NODES 100000
#define N_EDGES 800000
#define G_GRAPHS 64
#define F_INPUT 64
#define H_DIM 128
#define C_OUT 4
#define SCAN_BLOCKS ((N_NODES + 255) / 256)   // 391

typedef __attribute__((ext_vector_type(8))) short bf16x8;
typedef __attribute__((ext_vector_type(8))) unsigned short u16x8;
typedef __attribute__((ext_vector_type(4))) float f32x4;

__device__ inline unsigned short f2bf(float f) {
    union { float f; unsigned int u; } v; v.f = f;
    unsigned int u = v.u + 0x7FFFu + ((v.u >> 16) & 1u);
    return (unsigned short)(u >> 16);
}
__device__ inline float bf2f(unsigned short b) {
    union { unsigned int u; float f; } v; v.u = ((unsigned int)b) << 16;
    return v.f;
}
__device__ inline float2 unpack_pair(unsigned int u) {
    union { unsigned int u; float f; } a, b;
    a.u = u << 16; b.u = u & 0xFFFF0000u;
    float2 r; r.x = a.f; r.y = b.f; return r;
}

// ---------------------------------------------------------------------------
// CSR build
__global__ void hist_kernel(const int* __restrict__ dst, int* __restrict__ cnt) {
    int e = blockIdx.x * 256 + threadIdx.x;
    if (e < N_EDGES) atomicAdd(&cnt[dst[e]], 1);
}
__global__ __launch_bounds__(256) void scan1_kernel(
    const int* __restrict__ cnt, int* __restrict__ pre, int* __restrict__ bsum)
{
    __shared__ int tmp[256];
    int i = blockIdx.x * 256 + threadIdx.x;
    int v = (i < N_NODES) ? cnt[i] : 0;
    tmp[threadIdx.x] = v;
    __syncthreads();
    for (int off = 1; off < 256; off <<= 1) {
        int t = (threadIdx.x >= off) ? tmp[threadIdx.x - off] : 0;
        __syncthreads();
        tmp[threadIdx.x] += t;
        __syncthreads();
    }
    if (i < N_NODES) pre[i] = tmp[threadIdx.x] - v;
    if (threadIdx.x == 255) bsum[blockIdx.x] = tmp[255];
}
__global__ __launch_bounds__(512) void scan2_kernel(int* __restrict__ bsum) {
    __shared__ int t[SCAN_BLOCKS];
    int tid = threadIdx.x;
    if (tid < SCAN_BLOCKS) t[tid] = bsum[tid];
    __syncthreads();
    if (tid == 0) {
        int run = 0;
        for (int i = 0; i < SCAN_BLOCKS; i++) { int v = t[i]; t[i] = run; run += v; }
    }
    __syncthreads();
    if (tid < SCAN_BLOCKS) bsum[tid] = t[tid];
}
__global__ __launch_bounds__(256) void scan3_kernel(
    const int* __restrict__ pre, const int* __restrict__ bsum,
    const int* __restrict__ cnt, int* __restrict__ offs, float* __restrict__ dinv)
{
    int i = blockIdx.x * 256 + threadIdx.x;
    if (i < N_NODES) {
        offs[i] = pre[i] + bsum[blockIdx.x];
        dinv[i] = rsqrtf((float)cnt[i] + 1.0f);
    }
    if (i == 0) offs[N_NODES] = N_EDGES;
}
__global__ void fill_kernel(const int* __restrict__ src, const int* __restrict__ dst,
                            const int* __restrict__ offs, int* __restrict__ cnt,
                            int* __restrict__ csr)
{
    int e = blockIdx.x * 256 + threadIdx.x;
    if (e < N_EDGES) {
        int d = dst[e];
        int p = offs[d] + (atomicSub(&cnt[d], 1) - 1);
        csr[p] = src[e];
    }
}

// ---------------------------------------------------------------------------
// xb = bf16(x * dinv[row])   (x fp32 [N,64])
__global__ __launch_bounds__(256) void convert_x_kernel(
    const float4* __restrict__ x4, const float* __restrict__ dinv,
    unsigned int* __restrict__ xb_u)
{
    int i = blockIdx.x * 256 + threadIdx.x;   // N*64/4 = 1.6M
    if (i < N_NODES * F_INPUT / 4) {
        float dv = dinv[i >> 4];              // 16 float4 per row
        float4 v = x4[i];
        xb_u[i * 2 + 0] = (unsigned int)f2bf(v.x * dv) | ((unsigned int)f2bf(v.y * dv) << 16);
        xb_u[i * 2 + 1] = (unsigned int)f2bf(v.z * dv) | ((unsigned int)f2bf(v.w * dv) << 16);
    }
}

// W [K,H] fp32 -> split bf16 pair packed in MFMA B-fragment order:
// hi[((ct*KS+ks)*64+lane)*8 + j] = bf16(W[ks*32+(lane>>4)*8+j][ct*16+(lane&15)])
__global__ void wpack_kernel(const float* __restrict__ W, unsigned short* __restrict__ hi,
                             unsigned short* __restrict__ lo, int K)
{
    int t = blockIdx.x * 256 + threadIdx.x;       // (ct*KS+ks)*64+lane
    int total = (H_DIM / 16) * (K / 32) * 64;
    if (t >= total) return;
    int lane = t & 63;
    int tile = t >> 6;
    int KS = K / 32;
    int ct = tile / KS, ks = tile % KS;
    int n  = ct * 16 + (lane & 15);
    int k0 = ks * 32 + (lane >> 4) * 8;
    #pragma unroll
    for (int j = 0; j < 8; j++) {
        float w = W[(k0 + j) * H_DIM + n];
        unsigned short h = f2bf(w);
        hi[t * 8 + j] = h;
        lo[t * 8 + j] = f2bf(w - bf2f(h));
    }
}

// ---------------------------------------------------------------------------
// MFMA GEMM: out[N,H]bf16 = epilogue( in[N,K]bf16 @ (Whi+Wlo)[K,H] )
// EPI: BIAS_RELU -> relu(v + bias[col]);  else -> v * dinv[row]
// A staged in LDS fragment-contiguous; W read directly from packed global (L2-hot).
template <int K, bool BIAS_RELU>
__global__ __launch_bounds__(256) void mfma_gemm_kernel(
    const unsigned short* __restrict__ in, const unsigned short* __restrict__ whi,
    const unsigned short* __restrict__ wlo, const float* __restrict__ dinv,
    const float* __restrict__ bias, unsigned short* __restrict__ out)
{
    constexpr int KS = K / 32;
    __shared__ unsigned short As[128 * K];     // 32 KB (K=128) / 16 KB (K=64)

    const int tid  = threadIdx.x;
    const int row0 = blockIdx.x * 128;

    const int CH = 128 * K / 8;
    for (int c = tid; c < CH; c += 256) {
        int mt   = c / (KS * 64);
        int rest = c % (KS * 64);
        int ks   = rest / 64;
        int ln   = rest % 64;
        int r    = mt * 16 + (ln & 15);
        int k    = ks * 32 + (ln >> 4) * 8;
        int gr   = row0 + r; if (gr >= N_NODES) gr = N_NODES - 1;
        *(u16x8*)(As + c * 8) = *(const u16x8*)(in + (size_t)gr * K + k);
    }
    __syncthreads();

    const int w = tid >> 6, lane = tid & 63;
    const int quad = lane >> 4, l16 = lane & 15;

    f32x4 acc[2][8];
    #pragma unroll
    for (int rt = 0; rt < 2; rt++)
        #pragma unroll
        for (int ct = 0; ct < 8; ct++) acc[rt][ct] = (f32x4)(0.0f);

    #pragma unroll
    for (int ks = 0; ks < KS; ks++) {
        bf16x8 a0 = *(const bf16x8*)(As + (((w * 2 + 0) * KS + ks) * 64 + lane) * 8);
        bf16x8 a1 = *(const bf16x8*)(As + (((w * 2 + 1) * KS + ks) * 64 + lane) * 8);
        bf16x8 bh[8], bl[8];
        #pragma unroll
        for (int ct = 0; ct < 8; ct++) {
            bh[ct] = *(const bf16x8*)(whi + ((size_t)(ct * KS + ks) * 64 + lane) * 8);
            bl[ct] = *(const bf16x8*)(wlo + ((size_t)(ct * KS + ks) * 64 + lane) * 8);
        }
        #pragma unroll
        for (int ct = 0; ct < 8; ct++) {
            acc[0][ct] = __builtin_amdgcn_mfma_f32_16x16x32_bf16(a0, bh[ct], acc[0][ct], 0, 0, 0);
            acc[0][ct] = __builtin_amdgcn_mfma_f32_16x16x32_bf16(a0, bl[ct], acc[0][ct], 0, 0, 0);
            acc[1][ct] = __builtin_amdgcn_mfma_f32_16x16x32_bf16(a1, bh[ct], acc[1][ct], 0, 0, 0);
            acc[1][ct] = __builtin_amdgcn_mfma_f32_16x16x32_bf16(a1, bl[ct], acc[1][ct], 0, 0, 0);
        }
    }

    float bv[8];
    if (BIAS_RELU) {
        #pragma unroll
        for (int ct = 0; ct < 8; ct++) bv[ct] = bias[ct * 16 + l16];
    }

    #pragma unroll
    for (int rt = 0; rt < 2; rt++) {
        #pragma unroll
        for (int reg = 0; reg < 4; reg++) {
            int row = row0 + w * 32 + rt * 16 + quad * 4 + reg;
            if (row < N_NODES) {
                if (BIAS_RELU) {
                    #pragma unroll
                    for (int ct = 0; ct < 8; ct++)
                        out[(size_t)row * H_DIM + ct * 16 + l16] =
                            f2bf(fmaxf(acc[rt][ct][reg] + bv[ct], 0.0f));
                } else {
                    float dv = dinv[row];
                    #pragma unroll
                    for (int ct = 0; ct < 8; ct++)
                        out[(size_t)row * H_DIM + ct * 16 + l16] = f2bf(acc[rt][ct][reg] * dv);
                }
            }
        }
    }
}

// ---------------------------------------------------------------------------
// gather: out[i] = epi( dinv[i] * (hs[i] + sum_e hs[csr[e]]) )
// SHIFT: log2(feature-pairs per node) (5 -> 64-dim, 6 -> 128-dim).
// Unrolled 8/4/1 for independent loads in flight.
template <int SHIFT, bool RELU, bool BIAS>
__global__ __launch_bounds__(256) void gather_kernel(
    const unsigned int* __restrict__ hs_u, const int* __restrict__ offs,
    const int* __restrict__ csr, const float* __restrict__ dinv,
    const float* __restrict__ bias, unsigned int* __restrict__ outb)
{
    const int F2 = 1 << SHIFT;
    int idx = blockIdx.x * 256 + threadIdx.x;
    int i  = idx >> SHIFT;
    int f2 = idx & (F2 - 1);
    int beg = offs[i];
    int end = offs[i + 1];
    float2 acc = unpack_pair(hs_u[(size_t)i * F2 + f2]);
    int e = beg;
    while (e + 8 <= end) {
        int s0 = csr[e+0], s1 = csr[e+1], s2 = csr[e+2], s3 = csr[e+3];
        int s4 = csr[e+4], s5 = csr[e+5], s6 = csr[e+6], s7 = csr[e+7];
        float2 v0 = unpack_pair(hs_u[(size_t)s0 * F2 + f2]);
        float2 v1 = unpack_pair(hs_u[(size_t)s1 * F2 + f2]);
        float2 v2 = unpack_pair(hs_u[(size_t)s2 * F2 + f2]);
        float2 v3 = unpack_pair(hs_u[(size_t)s3 * F2 + f2]);
        float2 v4 = unpack_pair(hs_u[(size_t)s4 * F2 + f2]);
        float2 v5 = unpack_pair(hs_u[(size_t)s5 * F2 + f2]);
        float2 v6 = unpack_pair(hs_u[(size_t)s6 * F2 + f2]);
        float2 v7 = unpack_pair(hs_u[(size_t)s7 * F2 + f2]);
        acc.x += ((v0.x + v1.x) + (v2.x + v3.x)) + ((v4.x + v5.x) + (v6.x + v7.x));
        acc.y += ((v0.y + v1.y) + (v2.y + v3.y)) + ((v4.y + v5.y) + (v6.y + v7.y));
        e += 8;
    }
    if (e + 4 <= end) {
        int s0 = csr[e+0], s1 = csr[e+1], s2 = csr[e+2], s3 = csr[e+3];
        float2 v0 = unpack_pair(hs_u[(size_t)s0 * F2 + f2]);
        float2 v1 = unpack_pair(hs_u[(size_t)s1 * F2 + f2]);
        float2 v2 = unpack_pair(hs_u[(size_t)s2 * F2 + f2]);
        float2 v3 = unpack_pair(hs_u[(size_t)s3 * F2 + f2]);
        acc.x += (v0.x + v1.x) + (v2.x + v3.x);
        acc.y += (v0.y + v1.y) + (v2.y + v3.y);
        e += 4;
    }
    while (e < end) {
        int s = csr[e++];
        float2 v = unpack_pair(hs_u[(size_t)s * F2 + f2]);
        acc.x += v.x; acc.y += v.y;
    }
    float dv = dinv[i];
    float vx = acc.x * dv;
    float vy = acc.y * dv;
    if (BIAS) {
        float2 bvv = *(const float2*)(bias + f2 * 2);
        vx += bvv.x; vy += bvv.y;
    }
    if (RELU) { vx = fmaxf(vx, 0.0f); vy = fmaxf(vy, 0.0f); }
    outb[idx] = (unsigned int)f2bf(vx) | ((unsigned int)f2bf(vy) << 16);
}

// ---------------------------------------------------------------------------
// mean-pool per graph over bf16 node features (batch sorted -> run-accumulate)
__global__ __launch_bounds__(128) void pool_kernel(
    const unsigned short* __restrict__ A, const int* __restrict__ batch,
    float* __restrict__ s, float* __restrict__ cnt)
{
    const int RPB = 256;
    int row0 = blockIdx.x * RPB;
    int f = threadIdx.x;
    float acc = 0.0f;
    int cur = -1, c = 0;
    for (int r = 0; r < RPB; r++) {
        int row = row0 + r;
        if (row >= N_NODES) break;
        int g = batch[row];
        if (g != cur) {
            if (cur >= 0) {
                unsafeAtomicAdd(&s[cur * H_DIM + f], acc);
                if (f == 0) unsafeAtomicAdd(&cnt[cur], (float)c);
            }
            cur = g; acc = 0.0f; c = 0;
        }
        acc += bf2f(A[(size_t)row * H_DIM + f]);
        c++;
    }
    if (cur >= 0) {
        unsafeAtomicAdd(&s[cur * H_DIM + f], acc);
        if (f == 0) unsafeAtomicAdd(&cnt[cur], (float)c);
    }
}

// ---------------------------------------------------------------------------
__global__ __launch_bounds__(128) void mlp_kernel(
    const float* __restrict__ s, const float* __restrict__ cnt,
    const float* __restrict__ fw1, const float* __restrict__ fb1,
    const float* __restrict__ fw2, const float* __restrict__ fb2,
    float* __restrict__ out)
{
    __shared__ float p[H_DIM];
    __shared__ float z[H_DIM];
    int g = blockIdx.x;
    int f = threadIdx.x;
    float c = fmaxf(cnt[g], 1.0f);
    p[f] = s[g * H_DIM + f] / c;
    __syncthreads();
    float acc = fb1[f];
    for (int k = 0; k < H_DIM; k++) acc = fmaf(p[k], fw1[k * H_DIM + f], acc);
    z[f] = fmaxf(acc, 0.0f);
    __syncthreads();
    if (f < C_OUT) {
        float o = fb2[f];
        for (int k = 0; k < H_DIM; k++) o = fmaf(z[k], fw2[k * C_OUT + f], o);
        out[g * C_OUT + f] = o;
    }
}

// ---------------------------------------------------------------------------
extern "C" void kernel_launch(void* const* d_in, const int* in_sizes, int n_in,
                              void* d_out, int out_size, void* d_ws, size_t ws_size,
                              hipStream_t stream)
{
    const float* x   = (const float*)d_in[0];
    const float* W1  = (const float*)d_in[1];
    const float* b1  = (const float*)d_in[2];
    const float* W2  = (const float*)d_in[3];
    const float* b2  = (const float*)d_in[4];
    const float* W3  = (const float*)d_in[5];
    const float* b3  = (const float*)d_in[6];
    const float* fw1 = (const float*)d_in[7];
    const float* fb1 = (const float*)d_in[8];
    const float* fw2 = (const float*)d_in[9];
    const float* fb2 = (const float*)d_in[10];
    const int*   ei  = (const int*)d_in[11];
    const int*   bat = (const int*)d_in[12];
    const int* esrc = ei;
    const int* edst = ei + N_EDGES;
    float* out = (float*)d_out;

    // workspace layout
    char* ws = (char*)d_ws;
    unsigned short* bufA = (unsigned short*)ws;  ws += (size_t)N_NODES * H_DIM * 2;   // 25.6MB
    unsigned short* bufB = (unsigned short*)ws;  ws += (size_t)N_NODES * H_DIM * 2;   // 25.6MB
    unsigned short* xb   = (unsigned short*)ws;  ws += (size_t)N_NODES * F_INPUT * 2; // 12.8MB
    unsigned short* w1hi = (unsigned short*)ws;  ws += H_DIM * F_INPUT * 2;
    unsigned short* w1lo = (unsigned short*)ws;  ws += H_DIM * F_INPUT * 2;
    unsigned short* w2hi = (unsigned short*)ws;  ws += H_DIM * H_DIM * 2;
    unsigned short* w2lo = (unsigned short*)ws;  ws += H_DIM * H_DIM * 2;
    unsigned short* w3hi = (unsigned short*)ws;  ws += H_DIM * H_DIM * 2;
    unsigned short* w3lo = (unsigned short*)ws;  ws += H_DIM * H_DIM * 2;
    float* dinv = (float*)ws;  ws += N_NODES * 4;
    float* s    = (float*)ws;  ws += G_GRAPHS * H_DIM * 4;
    float* cnt  = (float*)ws;  ws += G_GRAPHS * 4;
    int* cnti   = (int*)ws;    ws += N_NODES * 4;
    int* pre    = (int*)ws;    ws += N_NODES * 4;
    int* offs   = (int*)ws;    ws += (N_NODES + 1) * 4;
    int* bsum   = (int*)ws;    ws += (SCAN_BLOCKS + 1) * 4;
    int* csr    = (int*)ws;    ws += (size_t)N_EDGES * 4;

    hipMemsetAsync(cnti, 0, N_NODES * sizeof(int), stream);
    hipMemsetAsync(s, 0, (G_GRAPHS * H_DIM + G_GRAPHS) * sizeof(float), stream);

    // CSR build + dinv
    const int egrid = (N_EDGES + 255) / 256;
    hist_kernel<<<egrid, 256, 0, stream>>>(edst, cnti);
    scan1_kernel<<<SCAN_BLOCKS, 256, 0, stream>>>(cnti, pre, bsum);
    scan2_kernel<<<1, 512, 0, stream>>>(bsum);
    scan3_kernel<<<SCAN_BLOCKS, 256, 0, stream>>>(pre, bsum, cnti, offs, dinv);
    fill_kernel<<<egrid, 256, 0, stream>>>(esrc, edst, offs, cnti, csr);

    // weight packing + x' = x*dinv conversion
    convert_x_kernel<<<(N_NODES * F_INPUT / 4 + 255) / 256, 256, 0, stream>>>(
        (const float4*)x, dinv, (unsigned int*)xb);
    wpack_kernel<<<4, 256, 0, stream>>>(W1, w1hi, w1lo, F_INPUT);   // 1024 threads
    wpack_kernel<<<8, 256, 0, stream>>>(W2, w2hi, w2lo, H_DIM);     // 2048 threads
    wpack_kernel<<<8, 256, 0, stream>>>(W3, w3hi, w3lo, H_DIM);

    const int gemm_grid = (N_NODES + 127) / 128;        // 782
    const int gath_grid128 = (N_NODES * 64) / 256;      // 25000
    const int gath_grid64  = (N_NODES * 32) / 256;      // 12500

    // layer 1: aggregate-first (64-dim), then GEMM with fused bias+relu
    gather_kernel<5, false, false><<<gath_grid64, 256, 0, stream>>>(
        (const unsigned int*)xb, offs, csr, dinv, nullptr, (unsigned int*)bufA);
    mfma_gemm_kernel<64, true><<<gemm_grid, 256, 0, stream>>>(
        bufA, w1hi, w1lo, dinv, b1, bufB);
    // layer 2: GEMM (dinv epilogue) then gather (bias+relu)
    mfma_gemm_kernel<128, false><<<gemm_grid, 256, 0, stream>>>(
        bufB, w2hi, w2lo, dinv, nullptr, bufA);
    gather_kernel<6, true, true><<<gath_grid128, 256, 0, stream>>>(
        (const unsigned int*)bufA, offs, csr, dinv, b2, (unsigned int*)bufB);
    // layer 3: GEMM (dinv epilogue) then gather (bias, no relu)
    mfma_gemm_kernel<128, false><<<gemm_grid, 256, 0, stream>>>(
        bufB, w3hi, w3lo, dinv, nullptr, bufA);
    gather_kernel<6, false, true><<<gath_grid128, 256, 0, stream>>>(
        (const unsigned int*)bufA, offs, csr, dinv, b3, (unsigned int*)bufB);

    // pool + MLP head
    pool_kernel<<<(N_NODES + 255) / 256, 128, 0, stream>>>(bufB, bat, s, cnt);
    mlp_kernel<<<G_GRAPHS, 128, 0, stream>>>(s, cnt, fw1, fb1, fw2, fb2, out);
}

// Round 5
// 413.352 us; speedup vs baseline: 3.5444x; 1.1395x over previous
//
#include <hip/hip_runtime.h>

#define N_NODES 100000
#define N_EDGES 800000
#define G_GRAPHS 64
#define F_INPUT 64
#define H_DIM 128
#define C_OUT 4
#define SCAN_BLOCKS ((N_NODES + 255) / 256)   // 391

typedef __attribute__((ext_vector_type(8))) short bf16x8;
typedef __attribute__((ext_vector_type(8))) unsigned short u16x8;
typedef __attribute__((ext_vector_type(4))) float f32x4;

__device__ inline unsigned short f2bf(float f) {
    union { float f; unsigned int u; } v; v.f = f;
    unsigned int u = v.u + 0x7FFFu + ((v.u >> 16) & 1u);
    return (unsigned short)(u >> 16);
}
__device__ inline float bf2f(unsigned short b) {
    union { unsigned int u; float f; } v; v.u = ((unsigned int)b) << 16;
    return v.f;
}
__device__ inline float2 unpack_pair(unsigned int u) {
    union { unsigned int u; float f; } a, b;
    a.u = u << 16; b.u = u & 0xFFFF0000u;
    float2 r; r.x = a.f; r.y = b.f; return r;
}

// ---------------------------------------------------------------------------
// CSR build
__global__ void hist_kernel(const int* __restrict__ dst, int* __restrict__ cnt) {
    int e = blockIdx.x * 256 + threadIdx.x;
    if (e < N_EDGES) atomicAdd(&cnt[dst[e]], 1);
}
__global__ __launch_bounds__(256) void scan1_kernel(
    const int* __restrict__ cnt, int* __restrict__ pre, int* __restrict__ bsum)
{
    __shared__ int tmp[256];
    int i = blockIdx.x * 256 + threadIdx.x;
    int v = (i < N_NODES) ? cnt[i] : 0;
    tmp[threadIdx.x] = v;
    __syncthreads();
    for (int off = 1; off < 256; off <<= 1) {
        int t = (threadIdx.x >= off) ? tmp[threadIdx.x - off] : 0;
        __syncthreads();
        tmp[threadIdx.x] += t;
        __syncthreads();
    }
    if (i < N_NODES) pre[i] = tmp[threadIdx.x] - v;
    if (threadIdx.x == 255) bsum[blockIdx.x] = tmp[255];
}
__global__ __launch_bounds__(512) void scan2_kernel(int* __restrict__ bsum) {
    __shared__ int t[SCAN_BLOCKS];
    int tid = threadIdx.x;
    if (tid < SCAN_BLOCKS) t[tid] = bsum[tid];
    __syncthreads();
    if (tid == 0) {
        int run = 0;
        for (int i = 0; i < SCAN_BLOCKS; i++) { int v = t[i]; t[i] = run; run += v; }
    }
    __syncthreads();
    if (tid < SCAN_BLOCKS) bsum[tid] = t[tid];
}
__global__ __launch_bounds__(256) void scan3_kernel(
    const int* __restrict__ pre, const int* __restrict__ bsum,
    const int* __restrict__ cnt, int* __restrict__ offs, float* __restrict__ dinv)
{
    int i = blockIdx.x * 256 + threadIdx.x;
    if (i < N_NODES) {
        offs[i] = pre[i] + bsum[blockIdx.x];
        dinv[i] = rsqrtf((float)cnt[i] + 1.0f);
    }
    if (i == 0) offs[N_NODES] = N_EDGES;
}
__global__ void fill_kernel(const int* __restrict__ src, const int* __restrict__ dst,
                            const int* __restrict__ offs, int* __restrict__ cnt,
                            int* __restrict__ csr)
{
    int e = blockIdx.x * 256 + threadIdx.x;
    if (e < N_EDGES) {
        int d = dst[e];
        int p = offs[d] + (atomicSub(&cnt[d], 1) - 1);
        csr[p] = src[e];
    }
}

// ---------------------------------------------------------------------------
// xb = bf16(x * dinv[row])   (x fp32 [N,64])
__global__ __launch_bounds__(256) void convert_x_kernel(
    const float4* __restrict__ x4, const float* __restrict__ dinv,
    unsigned int* __restrict__ xb_u)
{
    int i = blockIdx.x * 256 + threadIdx.x;   // N*64/4 = 1.6M
    if (i < N_NODES * F_INPUT / 4) {
        float dv = dinv[i >> 4];              // 16 float4 per row
        float4 v = x4[i];
        xb_u[i * 2 + 0] = (unsigned int)f2bf(v.x * dv) | ((unsigned int)f2bf(v.y * dv) << 16);
        xb_u[i * 2 + 1] = (unsigned int)f2bf(v.z * dv) | ((unsigned int)f2bf(v.w * dv) << 16);
    }
}

// W [K,H] fp32 -> split bf16 pair packed in MFMA B-fragment order
__global__ void wpack_kernel(const float* __restrict__ W, unsigned short* __restrict__ hi,
                             unsigned short* __restrict__ lo, int K)
{
    int t = blockIdx.x * 256 + threadIdx.x;       // (ct*KS+ks)*64+lane
    int total = (H_DIM / 16) * (K / 32) * 64;
    if (t >= total) return;
    int lane = t & 63;
    int tile = t >> 6;
    int KS = K / 32;
    int ct = tile / KS, ks = tile % KS;
    int n  = ct * 16 + (lane & 15);
    int k0 = ks * 32 + (lane >> 4) * 8;
    #pragma unroll
    for (int j = 0; j < 8; j++) {
        float w = W[(k0 + j) * H_DIM + n];
        unsigned short h = f2bf(w);
        hi[t * 8 + j] = h;
        lo[t * 8 + j] = f2bf(w - bf2f(h));
    }
}

// ---------------------------------------------------------------------------
// MFMA GEMM: out[N,H]bf16 = epilogue( in[N,K]bf16 @ (Whi+Wlo)[K,H] )
template <int K, bool BIAS_RELU>
__global__ __launch_bounds__(256) void mfma_gemm_kernel(
    const unsigned short* __restrict__ in, const unsigned short* __restrict__ whi,
    const unsigned short* __restrict__ wlo, const float* __restrict__ dinv,
    const float* __restrict__ bias, unsigned short* __restrict__ out)
{
    constexpr int KS = K / 32;
    __shared__ unsigned short As[128 * K];     // 32 KB (K=128) / 16 KB (K=64)

    const int tid  = threadIdx.x;
    const int row0 = blockIdx.x * 128;

    const int CH = 128 * K / 8;
    for (int c = tid; c < CH; c += 256) {
        int mt   = c / (KS * 64);
        int rest = c % (KS * 64);
        int ks   = rest / 64;
        int ln   = rest % 64;
        int r    = mt * 16 + (ln & 15);
        int k    = ks * 32 + (ln >> 4) * 8;
        int gr   = row0 + r; if (gr >= N_NODES) gr = N_NODES - 1;
        *(u16x8*)(As + c * 8) = *(const u16x8*)(in + (size_t)gr * K + k);
    }
    __syncthreads();

    const int w = tid >> 6, lane = tid & 63;
    const int quad = lane >> 4, l16 = lane & 15;

    f32x4 acc[2][8];
    #pragma unroll
    for (int rt = 0; rt < 2; rt++)
        #pragma unroll
        for (int ct = 0; ct < 8; ct++) acc[rt][ct] = (f32x4)(0.0f);

    #pragma unroll
    for (int ks = 0; ks < KS; ks++) {
        bf16x8 a0 = *(const bf16x8*)(As + (((w * 2 + 0) * KS + ks) * 64 + lane) * 8);
        bf16x8 a1 = *(const bf16x8*)(As + (((w * 2 + 1) * KS + ks) * 64 + lane) * 8);
        bf16x8 bh[8], bl[8];
        #pragma unroll
        for (int ct = 0; ct < 8; ct++) {
            bh[ct] = *(const bf16x8*)(whi + ((size_t)(ct * KS + ks) * 64 + lane) * 8);
            bl[ct] = *(const bf16x8*)(wlo + ((size_t)(ct * KS + ks) * 64 + lane) * 8);
        }
        #pragma unroll
        for (int ct = 0; ct < 8; ct++) {
            acc[0][ct] = __builtin_amdgcn_mfma_f32_16x16x32_bf16(a0, bh[ct], acc[0][ct], 0, 0, 0);
            acc[0][ct] = __builtin_amdgcn_mfma_f32_16x16x32_bf16(a0, bl[ct], acc[0][ct], 0, 0, 0);
            acc[1][ct] = __builtin_amdgcn_mfma_f32_16x16x32_bf16(a1, bh[ct], acc[1][ct], 0, 0, 0);
            acc[1][ct] = __builtin_amdgcn_mfma_f32_16x16x32_bf16(a1, bl[ct], acc[1][ct], 0, 0, 0);
        }
    }

    float bv[8];
    if (BIAS_RELU) {
        #pragma unroll
        for (int ct = 0; ct < 8; ct++) bv[ct] = bias[ct * 16 + l16];
    }

    #pragma unroll
    for (int rt = 0; rt < 2; rt++) {
        #pragma unroll
        for (int reg = 0; reg < 4; reg++) {
            int row = row0 + w * 32 + rt * 16 + quad * 4 + reg;
            if (row < N_NODES) {
                if (BIAS_RELU) {
                    #pragma unroll
                    for (int ct = 0; ct < 8; ct++)
                        out[(size_t)row * H_DIM + ct * 16 + l16] =
                            f2bf(fmaxf(acc[rt][ct][reg] + bv[ct], 0.0f));
                } else {
                    float dv = dinv[row];
                    #pragma unroll
                    for (int ct = 0; ct < 8; ct++)
                        out[(size_t)row * H_DIM + ct * 16 + l16] = f2bf(acc[rt][ct][reg] * dv);
                }
            }
        }
    }
}

// ---------------------------------------------------------------------------
// gather: out[i] = epi( dinv[i] * (hs[i] + sum_e hs[csr[e]]) )  unroll 8/4/1
template <int SHIFT, bool RELU, bool BIAS>
__global__ __launch_bounds__(256) void gather_kernel(
    const unsigned int* __restrict__ hs_u, const int* __restrict__ offs,
    const int* __restrict__ csr, const float* __restrict__ dinv,
    const float* __restrict__ bias, unsigned int* __restrict__ outb)
{
    const int F2 = 1 << SHIFT;
    int idx = blockIdx.x * 256 + threadIdx.x;
    int i  = idx >> SHIFT;
    int f2 = idx & (F2 - 1);
    int beg = offs[i];
    int end = offs[i + 1];
    float2 acc = unpack_pair(hs_u[(size_t)i * F2 + f2]);
    int e = beg;
    while (e + 8 <= end) {
        int s0 = csr[e+0], s1 = csr[e+1], s2 = csr[e+2], s3 = csr[e+3];
        int s4 = csr[e+4], s5 = csr[e+5], s6 = csr[e+6], s7 = csr[e+7];
        float2 v0 = unpack_pair(hs_u[(size_t)s0 * F2 + f2]);
        float2 v1 = unpack_pair(hs_u[(size_t)s1 * F2 + f2]);
        float2 v2 = unpack_pair(hs_u[(size_t)s2 * F2 + f2]);
        float2 v3 = unpack_pair(hs_u[(size_t)s3 * F2 + f2]);
        float2 v4 = unpack_pair(hs_u[(size_t)s4 * F2 + f2]);
        float2 v5 = unpack_pair(hs_u[(size_t)s5 * F2 + f2]);
        float2 v6 = unpack_pair(hs_u[(size_t)s6 * F2 + f2]);
        float2 v7 = unpack_pair(hs_u[(size_t)s7 * F2 + f2]);
        acc.x += ((v0.x + v1.x) + (v2.x + v3.x)) + ((v4.x + v5.x) + (v6.x + v7.x));
        acc.y += ((v0.y + v1.y) + (v2.y + v3.y)) + ((v4.y + v5.y) + (v6.y + v7.y));
        e += 8;
    }
    if (e + 4 <= end) {
        int s0 = csr[e+0], s1 = csr[e+1], s2 = csr[e+2], s3 = csr[e+3];
        float2 v0 = unpack_pair(hs_u[(size_t)s0 * F2 + f2]);
        float2 v1 = unpack_pair(hs_u[(size_t)s1 * F2 + f2]);
        float2 v2 = unpack_pair(hs_u[(size_t)s2 * F2 + f2]);
        float2 v3 = unpack_pair(hs_u[(size_t)s3 * F2 + f2]);
        acc.x += (v0.x + v1.x) + (v2.x + v3.x);
        acc.y += (v0.y + v1.y) + (v2.y + v3.y);
        e += 4;
    }
    while (e < end) {
        int s = csr[e++];
        float2 v = unpack_pair(hs_u[(size_t)s * F2 + f2]);
        acc.x += v.x; acc.y += v.y;
    }
    float dv = dinv[i];
    float vx = acc.x * dv;
    float vy = acc.y * dv;
    if (BIAS) {
        float2 bvv = *(const float2*)(bias + f2 * 2);
        vx += bvv.x; vy += bvv.y;
    }
    if (RELU) { vx = fmaxf(vx, 0.0f); vy = fmaxf(vy, 0.0f); }
    outb[idx] = (unsigned int)f2bf(vx) | ((unsigned int)f2bf(vy) << 16);
}

// ---------------------------------------------------------------------------
// mean-pool: 32 rows/block (grid 3125 exact). Fast path when the whole chunk
// is one graph (avg graph ~1562 nodes -> ~98% of blocks): 32 unrolled
// independent loads, one atomic per feature. Slow path: run-accumulate.
__global__ __launch_bounds__(128) void pool_kernel(
    const unsigned short* __restrict__ A, const int* __restrict__ batch,
    float* __restrict__ s, float* __restrict__ cnt)
{
    const int RPB = 32;
    int row0 = blockIdx.x * RPB;
    int f = threadIdx.x;
    int g0 = batch[row0];
    int g1 = batch[row0 + RPB - 1];
    if (g0 == g1) {
        float acc = 0.0f;
        #pragma unroll
        for (int r = 0; r < RPB; r++)
            acc += bf2f(A[(size_t)(row0 + r) * H_DIM + f]);
        unsafeAtomicAdd(&s[g0 * H_DIM + f], acc);
        if (f == 0) unsafeAtomicAdd(&cnt[g0], (float)RPB);
    } else {
        float acc = 0.0f;
        int cur = g0, c = 0;
        for (int r = 0; r < RPB; r++) {
            int g = batch[row0 + r];
            if (g != cur) {
                unsafeAtomicAdd(&s[cur * H_DIM + f], acc);
                if (f == 0) unsafeAtomicAdd(&cnt[cur], (float)c);
                cur = g; acc = 0.0f; c = 0;
            }
            acc += bf2f(A[(size_t)(row0 + r) * H_DIM + f]);
            c++;
        }
        unsafeAtomicAdd(&s[cur * H_DIM + f], acc);
        if (f == 0) unsafeAtomicAdd(&cnt[cur], (float)c);
    }
}

// ---------------------------------------------------------------------------
__global__ __launch_bounds__(128) void mlp_kernel(
    const float* __restrict__ s, const float* __restrict__ cnt,
    const float* __restrict__ fw1, const float* __restrict__ fb1,
    const float* __restrict__ fw2, const float* __restrict__ fb2,
    float* __restrict__ out)
{
    __shared__ float p[H_DIM];
    __shared__ float z[H_DIM];
    int g = blockIdx.x;
    int f = threadIdx.x;
    float c = fmaxf(cnt[g], 1.0f);
    p[f] = s[g * H_DIM + f] / c;
    __syncthreads();
    float acc = fb1[f];
    for (int k = 0; k < H_DIM; k++) acc = fmaf(p[k], fw1[k * H_DIM + f], acc);
    z[f] = fmaxf(acc, 0.0f);
    __syncthreads();
    if (f < C_OUT) {
        float o = fb2[f];
        for (int k = 0; k < H_DIM; k++) o = fmaf(z[k], fw2[k * C_OUT + f], o);
        out[g * C_OUT + f] = o;
    }
}

// ---------------------------------------------------------------------------
extern "C" void kernel_launch(void* const* d_in, const int* in_sizes, int n_in,
                              void* d_out, int out_size, void* d_ws, size_t ws_size,
                              hipStream_t stream)
{
    const float* x   = (const float*)d_in[0];
    const float* W1  = (const float*)d_in[1];
    const float* b1  = (const float*)d_in[2];
    const float* W2  = (const float*)d_in[3];
    const float* b2  = (const float*)d_in[4];
    const float* W3  = (const float*)d_in[5];
    const float* b3  = (const float*)d_in[6];
    const float* fw1 = (const float*)d_in[7];
    const float* fb1 = (const float*)d_in[8];
    const float* fw2 = (const float*)d_in[9];
    const float* fb2 = (const float*)d_in[10];
    const int*   ei  = (const int*)d_in[11];
    const int*   bat = (const int*)d_in[12];
    const int* esrc = ei;
    const int* edst = ei + N_EDGES;
    float* out = (float*)d_out;

    // workspace layout
    char* ws = (char*)d_ws;
    unsigned short* bufA = (unsigned short*)ws;  ws += (size_t)N_NODES * H_DIM * 2;   // 25.6MB
    unsigned short* bufB = (unsigned short*)ws;  ws += (size_t)N_NODES * H_DIM * 2;   // 25.6MB
    unsigned short* xb   = (unsigned short*)ws;  ws += (size_t)N_NODES * F_INPUT * 2; // 12.8MB
    unsigned short* w1hi = (unsigned short*)ws;  ws += H_DIM * F_INPUT * 2;
    unsigned short* w1lo = (unsigned short*)ws;  ws += H_DIM * F_INPUT * 2;
    unsigned short* w2hi = (unsigned short*)ws;  ws += H_DIM * H_DIM * 2;
    unsigned short* w2lo = (unsigned short*)ws;  ws += H_DIM * H_DIM * 2;
    unsigned short* w3hi = (unsigned short*)ws;  ws += H_DIM * H_DIM * 2;
    unsigned short* w3lo = (unsigned short*)ws;  ws += H_DIM * H_DIM * 2;
    float* dinv = (float*)ws;  ws += N_NODES * 4;
    float* s    = (float*)ws;  ws += G_GRAPHS * H_DIM * 4;
    float* cnt  = (float*)ws;  ws += G_GRAPHS * 4;
    int* cnti   = (int*)ws;    ws += N_NODES * 4;
    int* pre    = (int*)ws;    ws += N_NODES * 4;
    int* offs   = (int*)ws;    ws += (N_NODES + 1) * 4;
    int* bsum   = (int*)ws;    ws += (SCAN_BLOCKS + 1) * 4;
    int* csr    = (int*)ws;    ws += (size_t)N_EDGES * 4;

    hipMemsetAsync(cnti, 0, N_NODES * sizeof(int), stream);
    hipMemsetAsync(s, 0, (G_GRAPHS * H_DIM + G_GRAPHS) * sizeof(float), stream);

    // CSR build + dinv
    const int egrid = (N_EDGES + 255) / 256;
    hist_kernel<<<egrid, 256, 0, stream>>>(edst, cnti);
    scan1_kernel<<<SCAN_BLOCKS, 256, 0, stream>>>(cnti, pre, bsum);
    scan2_kernel<<<1, 512, 0, stream>>>(bsum);
    scan3_kernel<<<SCAN_BLOCKS, 256, 0, stream>>>(pre, bsum, cnti, offs, dinv);
    fill_kernel<<<egrid, 256, 0, stream>>>(esrc, edst, offs, cnti, csr);

    // weight packing + x' = x*dinv conversion
    convert_x_kernel<<<(N_NODES * F_INPUT / 4 + 255) / 256, 256, 0, stream>>>(
        (const float4*)x, dinv, (unsigned int*)xb);
    wpack_kernel<<<4, 256, 0, stream>>>(W1, w1hi, w1lo, F_INPUT);
    wpack_kernel<<<8, 256, 0, stream>>>(W2, w2hi, w2lo, H_DIM);
    wpack_kernel<<<8, 256, 0, stream>>>(W3, w3hi, w3lo, H_DIM);

    const int gemm_grid = (N_NODES + 127) / 128;        // 782
    const int gath_grid128 = (N_NODES * 64) / 256;      // 25000
    const int gath_grid64  = (N_NODES * 32) / 256;      // 12500

    // layer 1: aggregate-first (64-dim), then GEMM with fused bias+relu
    gather_kernel<5, false, false><<<gath_grid64, 256, 0, stream>>>(
        (const unsigned int*)xb, offs, csr, dinv, nullptr, (unsigned int*)bufA);
    mfma_gemm_kernel<64, true><<<gemm_grid, 256, 0, stream>>>(
        bufA, w1hi, w1lo, dinv, b1, bufB);
    // layer 2: GEMM (dinv epilogue) then gather (bias+relu)
    mfma_gemm_kernel<128, false><<<gemm_grid, 256, 0, stream>>>(
        bufB, w2hi, w2lo, dinv, nullptr, bufA);
    gather_kernel<6, true, true><<<gath_grid128, 256, 0, stream>>>(
        (const unsigned int*)bufA, offs, csr, dinv, b2, (unsigned int*)bufB);
    // layer 3: GEMM (dinv epilogue) then gather (bias, no relu)
    mfma_gemm_kernel<128, false><<<gemm_grid, 256, 0, stream>>>(
        bufB, w3hi, w3lo, dinv, nullptr, bufA);
    gather_kernel<6, false, true><<<gath_grid128, 256, 0, stream>>>(
        (const unsigned int*)bufA, offs, csr, dinv, b3, (unsigned int*)bufB);

    // pool + MLP head
    pool_kernel<<<N_NODES / 32, 128, 0, stream>>>(bufB, bat, s, cnt);
    mlp_kernel<<<G_GRAPHS, 128, 0, stream>>>(s, cnt, fw1, fb1, fw2, fb2, out);
}

// Round 6
// 395.370 us; speedup vs baseline: 3.7056x; 1.0455x over previous
//
#include <hip/hip_runtime.h>

#define N_NODES 100000
#define N_EDGES 800000
#define G_GRAPHS 64
#define F_INPUT 64
#define H_DIM 128
#define C_OUT 4
#define SCAN_BLOCKS ((N_NODES + 255) / 256)   // 391
#define FILL_SEG 8                             // dst ranges (one per XCD)
#define FILL_CHUNKS 125                        // edge chunks per range
#define FILL_RANGE (N_NODES / FILL_SEG)        // 12500
#define FILL_CHUNK (N_EDGES / FILL_CHUNKS)     // 6400

typedef __attribute__((ext_vector_type(8))) short bf16x8;
typedef __attribute__((ext_vector_type(8))) unsigned short u16x8;
typedef __attribute__((ext_vector_type(4))) float f32x4;

__device__ inline unsigned short f2bf(float f) {
    union { float f; unsigned int u; } v; v.f = f;
    unsigned int u = v.u + 0x7FFFu + ((v.u >> 16) & 1u);
    return (unsigned short)(u >> 16);
}
__device__ inline float bf2f(unsigned short b) {
    union { unsigned int u; float f; } v; v.u = ((unsigned int)b) << 16;
    return v.f;
}
__device__ inline float2 unpack_pair(unsigned int u) {
    union { unsigned int u; float f; } a, b;
    a.u = u << 16; b.u = u & 0xFFFF0000u;
    float2 r; r.x = a.f; r.y = b.f; return r;
}

// ---------------------------------------------------------------------------
// CSR build
__global__ void hist_kernel(const int* __restrict__ dst, int* __restrict__ cnt) {
    int e = blockIdx.x * 256 + threadIdx.x;
    if (e < N_EDGES) atomicAdd(&cnt[dst[e]], 1);
}
__global__ __launch_bounds__(256) void scan1_kernel(
    const int* __restrict__ cnt, int* __restrict__ pre, int* __restrict__ bsum)
{
    __shared__ int tmp[256];
    int i = blockIdx.x * 256 + threadIdx.x;
    int v = (i < N_NODES) ? cnt[i] : 0;
    tmp[threadIdx.x] = v;
    __syncthreads();
    for (int off = 1; off < 256; off <<= 1) {
        int t = (threadIdx.x >= off) ? tmp[threadIdx.x - off] : 0;
        __syncthreads();
        tmp[threadIdx.x] += t;
        __syncthreads();
    }
    if (i < N_NODES) pre[i] = tmp[threadIdx.x] - v;
    if (threadIdx.x == 255) bsum[blockIdx.x] = tmp[255];
}
// parallel exclusive scan of 391 block sums (Hillis-Steele over 512 threads)
__global__ __launch_bounds__(512) void scan2_kernel(int* __restrict__ bsum) {
    __shared__ int t[512];
    int tid = threadIdx.x;
    int v = (tid < SCAN_BLOCKS) ? bsum[tid] : 0;
    t[tid] = v;
    __syncthreads();
    for (int off = 1; off < 512; off <<= 1) {
        int u = (tid >= off) ? t[tid - off] : 0;
        __syncthreads();
        t[tid] += u;
        __syncthreads();
    }
    if (tid < SCAN_BLOCKS) bsum[tid] = t[tid] - v;   // exclusive
}
// offs = pre + bsum[block]; dinv = rsqrt(cnt+1); ALSO converts x -> bf16(x*dinv)
__global__ __launch_bounds__(256) void scan3x_kernel(
    const int* __restrict__ pre, const int* __restrict__ bsum,
    const int* __restrict__ cnt, const float4* __restrict__ x4,
    int* __restrict__ offs, float* __restrict__ dinv, unsigned int* __restrict__ xb_u)
{
    __shared__ float dl[256];
    int i = blockIdx.x * 256 + threadIdx.x;
    float dv = 0.0f;
    if (i < N_NODES) {
        offs[i] = pre[i] + bsum[blockIdx.x];
        dv = rsqrtf((float)cnt[i] + 1.0f);
        dinv[i] = dv;
    }
    if (i == 0) offs[N_NODES] = N_EDGES;
    dl[threadIdx.x] = dv;
    __syncthreads();
    const int row_base = blockIdx.x * 256;
    for (int c = threadIdx.x; c < 256 * 16; c += 256) {   // 16 float4 per row
        int r = c >> 4;
        int row = row_base + r;
        if (row < N_NODES) {
            float d2 = dl[r];
            float4 v = x4[(size_t)row * 16 + (c & 15)];
            size_t o = ((size_t)row * 16 + (c & 15)) * 2;
            xb_u[o + 0] = (unsigned int)f2bf(v.x * d2) | ((unsigned int)f2bf(v.y * d2) << 16);
            xb_u[o + 1] = (unsigned int)f2bf(v.z * d2) | ((unsigned int)f2bf(v.w * d2) << 16);
        }
    }
}
// XCD-partitioned CSR fill: blockIdx&7 selects a dst-range (round-robin -> one
// XCD owns each range's csr lines); blockIdx>>3 selects the edge chunk.
__global__ __launch_bounds__(256) void fill_kernel(
    const int* __restrict__ src, const int* __restrict__ dst,
    const int* __restrict__ offs, int* __restrict__ cnt, int* __restrict__ csr)
{
    const int r  = blockIdx.x & (FILL_SEG - 1);
    const int m  = blockIdx.x >> 3;
    const int lo = r * FILL_RANGE;
    const int hi = lo + FILL_RANGE;
    const int e0 = m * FILL_CHUNK;
    for (int e = e0 + threadIdx.x; e < e0 + FILL_CHUNK; e += 256) {
        int d = dst[e];
        if (d >= lo && d < hi) {
            int p = offs[d] + (atomicSub(&cnt[d], 1) - 1);
            csr[p] = src[e];
        }
    }
}

// ---------------------------------------------------------------------------
// all 3 weights -> split bf16 pairs packed in MFMA B-fragment order
__device__ inline void wpack_one(const float* __restrict__ W, unsigned short* __restrict__ hi,
                                 unsigned short* __restrict__ lo, int K, int t)
{
    int lane = t & 63;
    int tile = t >> 6;
    int KS = K / 32;
    int ct = tile / KS, ks = tile % KS;
    int n  = ct * 16 + (lane & 15);
    int k0 = ks * 32 + (lane >> 4) * 8;
    #pragma unroll
    for (int j = 0; j < 8; j++) {
        float w = W[(k0 + j) * H_DIM + n];
        unsigned short h = f2bf(w);
        hi[t * 8 + j] = h;
        lo[t * 8 + j] = f2bf(w - bf2f(h));
    }
}
__global__ __launch_bounds__(256) void wpack_all_kernel(
    const float* __restrict__ W1, const float* __restrict__ W2, const float* __restrict__ W3,
    unsigned short* __restrict__ w1hi, unsigned short* __restrict__ w1lo,
    unsigned short* __restrict__ w2hi, unsigned short* __restrict__ w2lo,
    unsigned short* __restrict__ w3hi, unsigned short* __restrict__ w3lo)
{
    int t = blockIdx.x * 256 + threadIdx.x;       // 0..5119
    if (t < 1024)       wpack_one(W1, w1hi, w1lo, F_INPUT, t);
    else if (t < 3072)  wpack_one(W2, w2hi, w2lo, H_DIM, t - 1024);
    else if (t < 5120)  wpack_one(W3, w3hi, w3lo, H_DIM, t - 3072);
}

// ---------------------------------------------------------------------------
// MFMA GEMM: out[N,H]bf16 = epilogue( in[N,K]bf16 @ (Whi+Wlo)[K,H] )
template <int K, bool BIAS_RELU>
__global__ __launch_bounds__(256) void mfma_gemm_kernel(
    const unsigned short* __restrict__ in, const unsigned short* __restrict__ whi,
    const unsigned short* __restrict__ wlo, const float* __restrict__ dinv,
    const float* __restrict__ bias, unsigned short* __restrict__ out)
{
    constexpr int KS = K / 32;
    __shared__ unsigned short As[128 * K];     // 32 KB (K=128) / 16 KB (K=64)

    const int tid  = threadIdx.x;
    const int row0 = blockIdx.x * 128;

    const int CH = 128 * K / 8;
    for (int c = tid; c < CH; c += 256) {
        int mt   = c / (KS * 64);
        int rest = c % (KS * 64);
        int ks   = rest / 64;
        int ln   = rest % 64;
        int r    = mt * 16 + (ln & 15);
        int k    = ks * 32 + (ln >> 4) * 8;
        int gr   = row0 + r; if (gr >= N_NODES) gr = N_NODES - 1;
        *(u16x8*)(As + c * 8) = *(const u16x8*)(in + (size_t)gr * K + k);
    }
    __syncthreads();

    const int w = tid >> 6, lane = tid & 63;
    const int quad = lane >> 4, l16 = lane & 15;

    f32x4 acc[2][8];
    #pragma unroll
    for (int rt = 0; rt < 2; rt++)
        #pragma unroll
        for (int ct = 0; ct < 8; ct++) acc[rt][ct] = (f32x4)(0.0f);

    #pragma unroll
    for (int ks = 0; ks < KS; ks++) {
        bf16x8 a0 = *(const bf16x8*)(As + (((w * 2 + 0) * KS + ks) * 64 + lane) * 8);
        bf16x8 a1 = *(const bf16x8*)(As + (((w * 2 + 1) * KS + ks) * 64 + lane) * 8);
        bf16x8 bh[8], bl[8];
        #pragma unroll
        for (int ct = 0; ct < 8; ct++) {
            bh[ct] = *(const bf16x8*)(whi + ((size_t)(ct * KS + ks) * 64 + lane) * 8);
            bl[ct] = *(const bf16x8*)(wlo + ((size_t)(ct * KS + ks) * 64 + lane) * 8);
        }
        #pragma unroll
        for (int ct = 0; ct < 8; ct++) {
            acc[0][ct] = __builtin_amdgcn_mfma_f32_16x16x32_bf16(a0, bh[ct], acc[0][ct], 0, 0, 0);
            acc[0][ct] = __builtin_amdgcn_mfma_f32_16x16x32_bf16(a0, bl[ct], acc[0][ct], 0, 0, 0);
            acc[1][ct] = __builtin_amdgcn_mfma_f32_16x16x32_bf16(a1, bh[ct], acc[1][ct], 0, 0, 0);
            acc[1][ct] = __builtin_amdgcn_mfma_f32_16x16x32_bf16(a1, bl[ct], acc[1][ct], 0, 0, 0);
        }
    }

    float bv[8];
    if (BIAS_RELU) {
        #pragma unroll
        for (int ct = 0; ct < 8; ct++) bv[ct] = bias[ct * 16 + l16];
    }

    #pragma unroll
    for (int rt = 0; rt < 2; rt++) {
        #pragma unroll
        for (int reg = 0; reg < 4; reg++) {
            int row = row0 + w * 32 + rt * 16 + quad * 4 + reg;
            if (row < N_NODES) {
                if (BIAS_RELU) {
                    #pragma unroll
                    for (int ct = 0; ct < 8; ct++)
                        out[(size_t)row * H_DIM + ct * 16 + l16] =
                            f2bf(fmaxf(acc[rt][ct][reg] + bv[ct], 0.0f));
                } else {
                    float dv = dinv[row];
                    #pragma unroll
                    for (int ct = 0; ct < 8; ct++)
                        out[(size_t)row * H_DIM + ct * 16 + l16] = f2bf(acc[rt][ct][reg] * dv);
                }
            }
        }
    }
}

// ---------------------------------------------------------------------------
// gather: out[i] = epi( dinv[i] * (hs[i] + sum_e hs[csr[e]]) )  unroll 8/4/1
template <int SHIFT, bool RELU, bool BIAS>
__global__ __launch_bounds__(256) void gather_kernel(
    const unsigned int* __restrict__ hs_u, const int* __restrict__ offs,
    const int* __restrict__ csr, const float* __restrict__ dinv,
    const float* __restrict__ bias, unsigned int* __restrict__ outb)
{
    const int F2 = 1 << SHIFT;
    int idx = blockIdx.x * 256 + threadIdx.x;
    int i  = idx >> SHIFT;
    int f2 = idx & (F2 - 1);
    int beg = offs[i];
    int end = offs[i + 1];
    float2 acc = unpack_pair(hs_u[(size_t)i * F2 + f2]);
    int e = beg;
    while (e + 8 <= end) {
        int s0 = csr[e+0], s1 = csr[e+1], s2 = csr[e+2], s3 = csr[e+3];
        int s4 = csr[e+4], s5 = csr[e+5], s6 = csr[e+6], s7 = csr[e+7];
        float2 v0 = unpack_pair(hs_u[(size_t)s0 * F2 + f2]);
        float2 v1 = unpack_pair(hs_u[(size_t)s1 * F2 + f2]);
        float2 v2 = unpack_pair(hs_u[(size_t)s2 * F2 + f2]);
        float2 v3 = unpack_pair(hs_u[(size_t)s3 * F2 + f2]);
        float2 v4 = unpack_pair(hs_u[(size_t)s4 * F2 + f2]);
        float2 v5 = unpack_pair(hs_u[(size_t)s5 * F2 + f2]);
        float2 v6 = unpack_pair(hs_u[(size_t)s6 * F2 + f2]);
        float2 v7 = unpack_pair(hs_u[(size_t)s7 * F2 + f2]);
        acc.x += ((v0.x + v1.x) + (v2.x + v3.x)) + ((v4.x + v5.x) + (v6.x + v7.x));
        acc.y += ((v0.y + v1.y) + (v2.y + v3.y)) + ((v4.y + v5.y) + (v6.y + v7.y));
        e += 8;
    }
    if (e + 4 <= end) {
        int s0 = csr[e+0], s1 = csr[e+1], s2 = csr[e+2], s3 = csr[e+3];
        float2 v0 = unpack_pair(hs_u[(size_t)s0 * F2 + f2]);
        float2 v1 = unpack_pair(hs_u[(size_t)s1 * F2 + f2]);
        float2 v2 = unpack_pair(hs_u[(size_t)s2 * F2 + f2]);
        float2 v3 = unpack_pair(hs_u[(size_t)s3 * F2 + f2]);
        acc.x += (v0.x + v1.x) + (v2.x + v3.x);
        acc.y += (v0.y + v1.y) + (v2.y + v3.y);
        e += 4;
    }
    while (e < end) {
        int s = csr[e++];
        float2 v = unpack_pair(hs_u[(size_t)s * F2 + f2]);
        acc.x += v.x; acc.y += v.y;
    }
    float dv = dinv[i];
    float vx = acc.x * dv;
    float vy = acc.y * dv;
    if (BIAS) {
        float2 bvv = *(const float2*)(bias + f2 * 2);
        vx += bvv.x; vy += bvv.y;
    }
    if (RELU) { vx = fmaxf(vx, 0.0f); vy = fmaxf(vy, 0.0f); }
    outb[idx] = (unsigned int)f2bf(vx) | ((unsigned int)f2bf(vy) << 16);
}

// ---------------------------------------------------------------------------
// mean-pool: 32 rows/block; fast path when chunk is single-graph (~98%)
__global__ __launch_bounds__(128) void pool_kernel(
    const unsigned short* __restrict__ A, const int* __restrict__ batch,
    float* __restrict__ s, float* __restrict__ cnt)
{
    const int RPB = 32;
    int row0 = blockIdx.x * RPB;
    int f = threadIdx.x;
    int g0 = batch[row0];
    int g1 = batch[row0 + RPB - 1];
    if (g0 == g1) {
        float acc = 0.0f;
        #pragma unroll
        for (int r = 0; r < RPB; r++)
            acc += bf2f(A[(size_t)(row0 + r) * H_DIM + f]);
        unsafeAtomicAdd(&s[g0 * H_DIM + f], acc);
        if (f == 0) unsafeAtomicAdd(&cnt[g0], (float)RPB);
    } else {
        float acc = 0.0f;
        int cur = g0, c = 0;
        for (int r = 0; r < RPB; r++) {
            int g = batch[row0 + r];
            if (g != cur) {
                unsafeAtomicAdd(&s[cur * H_DIM + f], acc);
                if (f == 0) unsafeAtomicAdd(&cnt[cur], (float)c);
                cur = g; acc = 0.0f; c = 0;
            }
            acc += bf2f(A[(size_t)(row0 + r) * H_DIM + f]);
            c++;
        }
        unsafeAtomicAdd(&s[cur * H_DIM + f], acc);
        if (f == 0) unsafeAtomicAdd(&cnt[cur], (float)c);
    }
}

// ---------------------------------------------------------------------------
__global__ __launch_bounds__(128) void mlp_kernel(
    const float* __restrict__ s, const float* __restrict__ cnt,
    const float* __restrict__ fw1, const float* __restrict__ fb1,
    const float* __restrict__ fw2, const float* __restrict__ fb2,
    float* __restrict__ out)
{
    __shared__ float p[H_DIM];
    __shared__ float z[H_DIM];
    int g = blockIdx.x;
    int f = threadIdx.x;
    float c = fmaxf(cnt[g], 1.0f);
    p[f] = s[g * H_DIM + f] / c;
    __syncthreads();
    float acc = fb1[f];
    for (int k = 0; k < H_DIM; k++) acc = fmaf(p[k], fw1[k * H_DIM + f], acc);
    z[f] = fmaxf(acc, 0.0f);
    __syncthreads();
    if (f < C_OUT) {
        float o = fb2[f];
        for (int k = 0; k < H_DIM; k++) o = fmaf(z[k], fw2[k * C_OUT + f], o);
        out[g * C_OUT + f] = o;
    }
}

// ---------------------------------------------------------------------------
extern "C" void kernel_launch(void* const* d_in, const int* in_sizes, int n_in,
                              void* d_out, int out_size, void* d_ws, size_t ws_size,
                              hipStream_t stream)
{
    const float* x   = (const float*)d_in[0];
    const float* W1  = (const float*)d_in[1];
    const float* b1  = (const float*)d_in[2];
    const float* W2  = (const float*)d_in[3];
    const float* b2  = (const float*)d_in[4];
    const float* W3  = (const float*)d_in[5];
    const float* b3  = (const float*)d_in[6];
    const float* fw1 = (const float*)d_in[7];
    const float* fb1 = (const float*)d_in[8];
    const float* fw2 = (const float*)d_in[9];
    const float* fb2 = (const float*)d_in[10];
    const int*   ei  = (const int*)d_in[11];
    const int*   bat = (const int*)d_in[12];
    const int* esrc = ei;
    const int* edst = ei + N_EDGES;
    float* out = (float*)d_out;

    // workspace layout
    char* ws = (char*)d_ws;
    unsigned short* bufA = (unsigned short*)ws;  ws += (size_t)N_NODES * H_DIM * 2;   // 25.6MB
    unsigned short* bufB = (unsigned short*)ws;  ws += (size_t)N_NODES * H_DIM * 2;   // 25.6MB
    unsigned short* xb   = (unsigned short*)ws;  ws += (size_t)N_NODES * F_INPUT * 2; // 12.8MB
    unsigned short* w1hi = (unsigned short*)ws;  ws += H_DIM * F_INPUT * 2;
    unsigned short* w1lo = (unsigned short*)ws;  ws += H_DIM * F_INPUT * 2;
    unsigned short* w2hi = (unsigned short*)ws;  ws += H_DIM * H_DIM * 2;
    unsigned short* w2lo = (unsigned short*)ws;  ws += H_DIM * H_DIM * 2;
    unsigned short* w3hi = (unsigned short*)ws;  ws += H_DIM * H_DIM * 2;
    unsigned short* w3lo = (unsigned short*)ws;  ws += H_DIM * H_DIM * 2;
    float* dinv = (float*)ws;  ws += N_NODES * 4;
    float* s    = (float*)ws;  ws += G_GRAPHS * H_DIM * 4;
    float* cnt  = (float*)ws;  ws += G_GRAPHS * 4;
    int* cnti   = (int*)ws;    ws += N_NODES * 4;
    int* pre    = (int*)ws;    ws += N_NODES * 4;
    int* offs   = (int*)ws;    ws += (N_NODES + 1) * 4;
    int* bsum   = (int*)ws;    ws += (SCAN_BLOCKS + 1) * 4;
    int* csr    = (int*)ws;    ws += (size_t)N_EDGES * 4;

    hipMemsetAsync(cnti, 0, N_NODES * sizeof(int), stream);
    hipMemsetAsync(s, 0, (G_GRAPHS * H_DIM + G_GRAPHS) * sizeof(float), stream);

    // CSR build + dinv + x conversion (fused into scan3x)
    const int egrid = (N_EDGES + 255) / 256;
    hist_kernel<<<egrid, 256, 0, stream>>>(edst, cnti);
    scan1_kernel<<<SCAN_BLOCKS, 256, 0, stream>>>(cnti, pre, bsum);
    scan2_kernel<<<1, 512, 0, stream>>>(bsum);
    scan3x_kernel<<<SCAN_BLOCKS, 256, 0, stream>>>(
        pre, bsum, cnti, (const float4*)x, offs, dinv, (unsigned int*)xb);
    fill_kernel<<<FILL_SEG * FILL_CHUNKS, 256, 0, stream>>>(esrc, edst, offs, cnti, csr);

    wpack_all_kernel<<<20, 256, 0, stream>>>(W1, W2, W3, w1hi, w1lo, w2hi, w2lo, w3hi, w3lo);

    const int gemm_grid = (N_NODES + 127) / 128;        // 782
    const int gath_grid128 = (N_NODES * 64) / 256;      // 25000
    const int gath_grid64  = (N_NODES * 32) / 256;      // 12500

    // layer 1: aggregate-first (64-dim), then GEMM with fused bias+relu
    gather_kernel<5, false, false><<<gath_grid64, 256, 0, stream>>>(
        (const unsigned int*)xb, offs, csr, dinv, nullptr, (unsigned int*)bufA);
    mfma_gemm_kernel<64, true><<<gemm_grid, 256, 0, stream>>>(
        bufA, w1hi, w1lo, dinv, b1, bufB);
    // layer 2: GEMM (dinv epilogue) then gather (bias+relu)
    mfma_gemm_kernel<128, false><<<gemm_grid, 256, 0, stream>>>(
        bufB, w2hi, w2lo, dinv, nullptr, bufA);
    gather_kernel<6, true, true><<<gath_grid128, 256, 0, stream>>>(
        (const unsigned int*)bufA, offs, csr, dinv, b2, (unsigned int*)bufB);
    // layer 3: GEMM (dinv epilogue) then gather (bias, no relu)
    mfma_gemm_kernel<128, false><<<gemm_grid, 256, 0, stream>>>(
        bufB, w3hi, w3lo, dinv, nullptr, bufA);
    gather_kernel<6, false, true><<<gath_grid128, 256, 0, stream>>>(
        (const unsigned int*)bufA, offs, csr, dinv, b3, (unsigned int*)bufB);

    // pool + MLP head
    pool_kernel<<<N_NODES / 32, 128, 0, stream>>>(bufB, bat, s, cnt);
    mlp_kernel<<<G_GRAPHS, 128, 0, stream>>>(s, cnt, fw1, fb1, fw2, fb2, out);
}